// Round 2
// baseline (1101.784 us; speedup 1.0000x reference)
//
#include <hip/hip_runtime.h>
#include <cstdint>

typedef unsigned short u16;

#define AVG_LOG_F 1.4862356961977451f

// ---- workspace float-unit offsets (weights region) ----
#define OFF_W1   0      // pre_w1  fp32 [4][48][16]
#define OFF_W2   3072   // pre_w2  fp32 [4][16][16]
#define OFF_PW1  4096   // post_w1 fp32 [4][256][16]
#define OFF_PW2  20480  // post_w2 fp32 [4][16][16]
#define OFF_LW   21504  // lin_w   fp32 [64][64]
#define OFF_PB1  25600
#define OFF_PB2  25664
#define OFF_QB1  25728
#define OFF_QB2  25792
#define OFF_LB   25856
#define OFF_LG   25920
#define OFF_LBN  25984
#define OFF_ET   26048  // e_table fp32 [5][16]
#define IB       26176  // int region start (4B units); IB%4==0

__device__ __forceinline__ float bf2f(u16 u) {
    return __uint_as_float(((unsigned)u) << 16);
}
__device__ __forceinline__ u16 f2bf(float f) {
    unsigned u = __float_as_uint(f);
    u += 0x7fffu + ((u >> 16) & 1u);   // RNE
    return (u16)(u >> 16);
}
// generic scalar read of input element j: mode 0 = bf16, 1 = fp32
__device__ __forceinline__ float rdin(const void* p, int j, int mode) {
    if (mode == 0) return bf2f(((const u16*)p)[j]);
    return ((const float*)p)[j];
}
// 16-element vector read at element offset base (base*elt is 16B aligned in both modes)
__device__ __forceinline__ void load16(const void* p, long base, int mode, float* o) {
    if (mode == 0) {
        const u16* q = (const u16*)p + base;
        uint4 a = *(const uint4*)q;
        uint4 b = *(const uint4*)(q + 8);
        o[0]  = __uint_as_float(a.x << 16); o[1]  = __uint_as_float(a.x & 0xffff0000u);
        o[2]  = __uint_as_float(a.y << 16); o[3]  = __uint_as_float(a.y & 0xffff0000u);
        o[4]  = __uint_as_float(a.z << 16); o[5]  = __uint_as_float(a.z & 0xffff0000u);
        o[6]  = __uint_as_float(a.w << 16); o[7]  = __uint_as_float(a.w & 0xffff0000u);
        o[8]  = __uint_as_float(b.x << 16); o[9]  = __uint_as_float(b.x & 0xffff0000u);
        o[10] = __uint_as_float(b.y << 16); o[11] = __uint_as_float(b.y & 0xffff0000u);
        o[12] = __uint_as_float(b.z << 16); o[13] = __uint_as_float(b.z & 0xffff0000u);
        o[14] = __uint_as_float(b.w << 16); o[15] = __uint_as_float(b.w & 0xffff0000u);
    } else {
        const float* q = (const float*)p + base;
        float4 a = *(const float4*)q;
        float4 b = *(const float4*)(q + 4);
        float4 c = *(const float4*)(q + 8);
        float4 d = *(const float4*)(q + 12);
        o[0]=a.x; o[1]=a.y; o[2]=a.z; o[3]=a.w;
        o[4]=b.x; o[5]=b.y; o[6]=b.z; o[7]=b.w;
        o[8]=c.x; o[9]=c.y; o[10]=c.z; o[11]=c.w;
        o[12]=d.x; o[13]=d.y; o[14]=d.z; o[15]=d.w;
    }
}

// ---------------- 0: dtype detect ----------------
__global__ __launch_bounds__(256) void k_detect(const void* ax, int* modep) {
    __shared__ int csh;
    int tid = threadIdx.x;
    if (tid == 0) csh = 0;
    __syncthreads();
    unsigned v = ((const unsigned*)ax)[tid];
    unsigned lo = v & 0xffffu;
    int e = (int)((lo >> 7) & 0xff);
    int isbf = (lo == 0u) || (e >= 110 && e <= 140);
    atomicAdd(&csh, isbf);
    __syncthreads();
    if (tid == 0) modep[0] = (csh >= 192) ? 0 : 1;
}

// ---------------- 1: zero counters ----------------
__global__ __launch_bounds__(256) void k_zero(int* p, int n) {
    int i = blockIdx.x * 256 + threadIdx.x;
    if (i < n) p[i] = 0;
}

// ---------------- 2: weights -> fp32 in ws, edge table ----------------
__global__ __launch_bounds__(256) void k_prep(
    const void* bond_emb, const void* edge_w, const void* edge_b,
    const void* pre_w1, const void* pre_b1, const void* pre_w2, const void* pre_b2,
    const void* post_w1, const void* post_b1, const void* post_w2, const void* post_b2,
    const void* lin_w, const void* lin_b, const void* ln_g, const void* ln_b,
    float* wsf, const int* modep)
{
    int mode = modep[0];
    int gt = blockIdx.x * blockDim.x + threadIdx.x;
    int gs = gridDim.x * blockDim.x;
    for (int j = gt; j < 3072; j += gs)  wsf[OFF_W1 + j]  = rdin(pre_w1, j, mode);
    for (int j = gt; j < 1024; j += gs)  wsf[OFF_W2 + j]  = rdin(pre_w2, j, mode);
    for (int j = gt; j < 16384; j += gs) wsf[OFF_PW1 + j] = rdin(post_w1, j, mode);
    for (int j = gt; j < 1024; j += gs)  wsf[OFF_PW2 + j] = rdin(post_w2, j, mode);
    for (int j = gt; j < 4096; j += gs)  wsf[OFF_LW + j]  = rdin(lin_w, j, mode);
    for (int j = gt; j < 64; j += gs) {
        wsf[OFF_PB1 + j] = rdin(pre_b1, j, mode);
        wsf[OFF_PB2 + j] = rdin(pre_b2, j, mode);
        wsf[OFF_QB1 + j] = rdin(post_b1, j, mode);
        wsf[OFF_QB2 + j] = rdin(post_b2, j, mode);
        wsf[OFF_LB + j]  = rdin(lin_b, j, mode);
        wsf[OFF_LG + j]  = rdin(ln_g, j, mode);
        wsf[OFF_LBN + j] = rdin(ln_b, j, mode);
    }
    if (gt < 80) {
        int b = gt >> 4, f = gt & 15;
        float acc = rdin(edge_b, f, mode);
        for (int k = 0; k < 64; k++)
            acc = fmaf(rdin(bond_emb, b * 64 + k, mode), rdin(edge_w, k * 16 + f, mode), acc);
        wsf[OFF_ET + gt] = acc;
    }
}

// ---------------- 3: degree count ----------------
__global__ __launch_bounds__(256) void k_count(const int* __restrict__ dstp, int* __restrict__ cnt, int E) {
    int e = blockIdx.x * 256 + threadIdx.x;
    if (e < E) atomicAdd(&cnt[dstp[e]], 1);
}

// ---------------- 4a: per-256-chunk inclusive scan ----------------
__global__ __launch_bounds__(256) void k_scan1(const int* __restrict__ cnt, int* __restrict__ offs,
                                               int* __restrict__ bsum, int Nn) {
    __shared__ int sh[256];
    int tid = threadIdx.x;
    int i = blockIdx.x * 256 + tid;
    int v = (i < Nn) ? cnt[i] : 0;
    sh[tid] = v;
    __syncthreads();
    for (int o = 1; o < 256; o <<= 1) {
        int u = (tid >= o) ? sh[tid - o] : 0;
        __syncthreads();
        sh[tid] += u;
        __syncthreads();
    }
    if (i < Nn) offs[i] = sh[tid];
    if (tid == 255) bsum[blockIdx.x] = sh[255];
}

// ---------------- 4b: scan the block sums (single block; NB <= 256) ----------------
__global__ __launch_bounds__(256) void k_scan2(int* __restrict__ bsum, int NB) {
    __shared__ int sh[256];
    int tid = threadIdx.x;
    int v = (tid < NB) ? bsum[tid] : 0;
    sh[tid] = v;
    __syncthreads();
    for (int o = 1; o < 256; o <<= 1) {
        int u = (tid >= o) ? sh[tid - o] : 0;
        __syncthreads();
        sh[tid] += u;
        __syncthreads();
    }
    if (tid < NB) bsum[tid] = sh[tid];
}

// ---------------- 4c: finalize exclusive offsets, cursor, degree hist ----------------
__global__ __launch_bounds__(256) void k_scan3(int* __restrict__ offs, const int* __restrict__ cnt,
                                               int* __restrict__ cursor, int* __restrict__ hist,
                                               const int* __restrict__ bsum, int Nn, int E) {
    int tid = threadIdx.x, b = blockIdx.x;
    int base = (b > 0) ? bsum[b - 1] : 0;
    int i = b * 256 + tid;
    if (i < Nn) {
        int c = cnt[i];
        int st = offs[i] - c + base;
        offs[i] = st;
        cursor[i] = st;
        atomicAdd(&hist[c < 63 ? c : 63], 1);
    }
    if (i == 0) offs[Nn] = E;
}

// ---------------- 5: degree-sorted node order ----------------
__global__ __launch_bounds__(256) void k_order(const int* __restrict__ cnt, const int* __restrict__ hist,
                                               int* __restrict__ hcnt, int* __restrict__ norder, int Nn) {
    __shared__ int hbase[64];
    int tid = threadIdx.x;
    if (tid < 64) {
        int v = hist[tid];
        int orig = v;
        for (int o = 1; o < 64; o <<= 1) { int u = __shfl_up(v, o); if (tid >= o) v += u; }
        hbase[tid] = v - orig;
    }
    __syncthreads();
    int i = blockIdx.x * 256 + tid;
    if (i < Nn) {
        int c = cnt[i];
        int bin = c < 63 ? c : 63;
        int pos = hbase[bin] + atomicAdd(&hcnt[bin], 1);
        norder[pos] = i;
    }
}

// ---------------- 6: CSR scatter ----------------
__global__ __launch_bounds__(256) void k_scatter(const int* __restrict__ dstp, int* __restrict__ cursor,
                                                 int* __restrict__ perm, int E) {
    int e = blockIdx.x * 256 + threadIdx.x;
    if (e < E) {
        int pos = atomicAdd(&cursor[dstp[e]], 1);
        perm[pos] = e;
    }
}

// ---------------- 7: fused messages + aggregation + post-MLP ----------------
__device__ __forceinline__ void statblk(const float a[16], const float* __restrict__ PW1, int blkbase,
                                        float sc1, float sc2, float p1[16]) {
#pragma unroll
    for (int f = 0; f < 16; f++) {
        float av = a[f];
#pragma unroll
        for (int g = 0; g < 16; g++) {
            float w = fmaf(sc2, PW1[(176 + blkbase + f) * 16 + g],
                     fmaf(sc1, PW1[(96 + blkbase + f) * 16 + g],
                               PW1[(16 + blkbase + f) * 16 + g]));
            p1[g] = fmaf(av, w, p1[g]);
        }
    }
}

__global__ __launch_bounds__(256) void k_node(
    const void* __restrict__ ax, const int* __restrict__ srcp, const int* __restrict__ bondp,
    const int* __restrict__ offs, const int* __restrict__ perm, const int* __restrict__ norder,
    const float* __restrict__ wsf, u16* __restrict__ p2h, const int* __restrict__ modep, int Nn)
{
    int i = blockIdx.x * 256 + threadIdx.x;
    if (i >= Nn) return;
    int mode = modep[0];
    int t = blockIdx.y;
    int n = norder[i];
    int start = offs[n];
    int deg = offs[n + 1] - start;

    const float* W1  = wsf + OFF_W1  + t * 768;
    const float* W2  = wsf + OFF_W2  + t * 256;
    const float* PW1 = wsf + OFF_PW1 + t * 4096;
    const float* PW2 = wsf + OFF_PW2 + t * 256;
    const float* PB1 = wsf + OFF_PB1 + t * 16;
    const float* PB2 = wsf + OFF_PB2 + t * 16;
    const float* QB1 = wsf + OFF_QB1 + t * 16;
    const float* QB2 = wsf + OFF_QB2 + t * 16;
    const float* ET  = wsf + OFF_ET;

    float xi[16];
    load16(ax, (long)n * 64 + t * 16, mode, xi);

    float s[16], s2[16], mn[16], mx[16];
#pragma unroll
    for (int g = 0; g < 16; g++) { s[g] = 0.f; s2[g] = 0.f; mn[g] = 3.0e38f; mx[g] = -3.0e38f; }

    for (int k = 0; k < deg; k++) {
        int e = perm[start + k];
        int sn = srcp[e];
        int bd = bondp[e];
        float xj[16];
        load16(ax, (long)sn * 64 + t * 16, mode, xj);
        float ev[16];
        {
            const float4* ep = (const float4*)(ET + bd * 16);
            float4 e0 = ep[0], e1 = ep[1], e2 = ep[2], e3 = ep[3];
            ev[0] = e0.x; ev[1] = e0.y; ev[2] = e0.z; ev[3] = e0.w;
            ev[4] = e1.x; ev[5] = e1.y; ev[6] = e1.z; ev[7] = e1.w;
            ev[8] = e2.x; ev[9] = e2.y; ev[10] = e2.z; ev[11] = e2.w;
            ev[12] = e3.x; ev[13] = e3.y; ev[14] = e3.z; ev[15] = e3.w;
        }
        float h1[16];
#pragma unroll
        for (int g = 0; g < 16; g++) h1[g] = PB1[g];
#pragma unroll
        for (int f = 0; f < 16; f++) {
            float a = xi[f], b = xj[f], c = ev[f];
#pragma unroll
            for (int g = 0; g < 16; g++)
                h1[g] = fmaf(a, W1[f * 16 + g],
                        fmaf(b, W1[(16 + f) * 16 + g],
                        fmaf(c, W1[(32 + f) * 16 + g], h1[g])));
        }
#pragma unroll
        for (int f = 0; f < 16; f++) h1[f] = fmaxf(h1[f], 0.f);
#pragma unroll
        for (int g = 0; g < 16; g++) {
            float m = PB2[g];
#pragma unroll
            for (int f = 0; f < 16; f++) m = fmaf(h1[f], W2[f * 16 + g], m);
            s[g] += m;
            s2[g] = fmaf(m, m, s2[g]);
            mn[g] = fminf(mn[g], m);
            mx[g] = fmaxf(mx[g], m);
        }
    }

    if (deg == 0) {
#pragma unroll
        for (int g = 0; g < 16; g++) { mn[g] = 0.f; mx[g] = 0.f; }
    }
    float cf = (float)(deg > 0 ? deg : 1);
    float inv = 1.0f / cf;
    float mean[16], sd[16];
#pragma unroll
    for (int g = 0; g < 16; g++) {
        mean[g] = s[g] * inv;
        float m2 = s2[g] * inv;
        float v = m2 - mean[g] * mean[g];
        sd[g] = sqrtf(fmaxf(v, 0.f) + 1e-5f);
    }
    float ldv = logf(cf + 1.0f);
    float sc1 = ldv * (1.0f / AVG_LOG_F);
    float sc2 = AVG_LOG_F / ldv;

    float p1[16];
#pragma unroll
    for (int g = 0; g < 16; g++) p1[g] = QB1[g];
#pragma unroll
    for (int f = 0; f < 16; f++) {
        float a = xi[f];
#pragma unroll
        for (int g = 0; g < 16; g++) p1[g] = fmaf(a, PW1[f * 16 + g], p1[g]);
    }
    statblk(s,    PW1, 0,  sc1, sc2, p1);
    statblk(mean, PW1, 16, sc1, sc2, p1);
    statblk(mn,   PW1, 32, sc1, sc2, p1);
    statblk(mx,   PW1, 48, sc1, sc2, p1);
    statblk(sd,   PW1, 64, sc1, sc2, p1);
#pragma unroll
    for (int f = 0; f < 16; f++) p1[f] = fmaxf(p1[f], 0.f);

    float m[16];
#pragma unroll
    for (int g = 0; g < 16; g++) {
        float acc = QB2[g];
#pragma unroll
        for (int f = 0; f < 16; f++) acc = fmaf(p1[f], PW2[f * 16 + g], acc);
        m[g] = acc;
    }
    // pack 16 bf16 -> 2x uint4 stores
    uint4 A, B;
    A.x = (unsigned)f2bf(m[0])  | ((unsigned)f2bf(m[1])  << 16);
    A.y = (unsigned)f2bf(m[2])  | ((unsigned)f2bf(m[3])  << 16);
    A.z = (unsigned)f2bf(m[4])  | ((unsigned)f2bf(m[5])  << 16);
    A.w = (unsigned)f2bf(m[6])  | ((unsigned)f2bf(m[7])  << 16);
    B.x = (unsigned)f2bf(m[8])  | ((unsigned)f2bf(m[9])  << 16);
    B.y = (unsigned)f2bf(m[10]) | ((unsigned)f2bf(m[11]) << 16);
    B.z = (unsigned)f2bf(m[12]) | ((unsigned)f2bf(m[13]) << 16);
    B.w = (unsigned)f2bf(m[14]) | ((unsigned)f2bf(m[15]) << 16);
    uint4* dst = (uint4*)(p2h + (long)n * 64 + t * 16);
    dst[0] = A;
    dst[1] = B;
}

// ---------------- 8: 64x64 linear + LayerNorm + ReLU + residual ----------------
__global__ __launch_bounds__(256) void k_final(
    const void* __restrict__ ax, const float* __restrict__ wsf,
    const u16* __restrict__ p2h, void* __restrict__ outp, const int* __restrict__ modep, int Nn)
{
    int tid = threadIdx.x;
    int wid = (blockIdx.x * 256 + tid) >> 6;
    int l = tid & 63;
    int mode = modep[0];
    int n0 = wid * 4;
    if (n0 >= Nn) return;
    const float* LW = wsf + OFF_LW;
    float lb = wsf[OFF_LB + l];
    const u16* r0 = p2h + (long)n0 * 64;
    float a0 = lb, a1 = lb, a2 = lb, a3 = lb;
#pragma unroll
    for (int f = 0; f < 64; f++) {
        float w = LW[f * 64 + l];
        a0 = fmaf(bf2f(r0[f]),       w, a0);
        a1 = fmaf(bf2f(r0[64 + f]),  w, a1);
        a2 = fmaf(bf2f(r0[128 + f]), w, a2);
        a3 = fmaf(bf2f(r0[192 + f]), w, a3);
    }
    float g = wsf[OFF_LG + l], be = wsf[OFF_LBN + l];
    float acc[4] = {a0, a1, a2, a3};
#pragma unroll
    for (int j = 0; j < 4; j++) {
        if (n0 + j >= Nn) break;
        float v = acc[j];
        float s1 = v, sq = v * v;
#pragma unroll
        for (int o = 1; o < 64; o <<= 1) { s1 += __shfl_xor(s1, o); sq += __shfl_xor(sq, o); }
        float mu = s1 * (1.0f / 64.0f);
        float var = sq * (1.0f / 64.0f) - mu * mu;
        float ln = (v - mu) * rsqrtf(var + 1e-5f) * g + be;
        long idx = (long)(n0 + j) * 64 + l;
        float res = rdin(ax, (int)idx, mode) + fmaxf(ln, 0.f);
        if (mode == 0) ((u16*)outp)[idx] = f2bf(res);
        else           ((float*)outp)[idx] = res;
    }
}

// ---------------- 9: diagnostic marker (no-op when pipeline is healthy) ----------------
__global__ __launch_bounds__(64) void k_marker(
    const float* __restrict__ wsf, const int* __restrict__ offs, const int* __restrict__ perm,
    const u16* __restrict__ p2h, void* __restrict__ outp, const int* __restrict__ modep,
    int Nn, int E)
{
    if (threadIdx.x != 0 || blockIdx.x != 0) return;
    int code = 0;
    if (__float_as_uint(wsf[OFF_W1 + 5]) == 0xAAAAAAAAu) code |= 1;   // k_prep dead
    if (offs[Nn] != E) code |= 2;                                     // scan dead
    if (((const unsigned*)perm)[0] == 0xAAAAAAAAu &&
        ((const unsigned*)perm)[1] == 0xAAAAAAAAu) code |= 4;         // scatter dead
    if (p2h[0] == 0xAAAAu && p2h[1] == 0xAAAAu &&
        p2h[2] == 0xAAAAu && p2h[3] == 0xAAAAu) code |= 8;            // k_node dead
    if (code != 0) {
        float val = 1024.0f * (float)code;
        if (modep[0] == 0) ((u16*)outp)[0] = f2bf(val);
        else               ((float*)outp)[0] = val;
    }
}

extern "C" void kernel_launch(void* const* d_in, const int* in_sizes, int n_in,
                              void* d_out, int out_size, void* d_ws, size_t ws_size,
                              hipStream_t stream) {
    const void* atom_x   = d_in[0];
    const void* bond_emb = d_in[1];
    const void* edge_w   = d_in[2];
    const void* edge_b   = d_in[3];
    const void* pre_w1   = d_in[4];
    const void* pre_b1   = d_in[5];
    const void* pre_w2   = d_in[6];
    const void* pre_b2   = d_in[7];
    const void* post_w1  = d_in[8];
    const void* post_b1  = d_in[9];
    const void* post_w2  = d_in[10];
    const void* post_b2  = d_in[11];
    const void* lin_w    = d_in[12];
    const void* lin_b    = d_in[13];
    const void* ln_g     = d_in[14];
    const void* ln_b     = d_in[15];
    const int* bond_x    = (const int*)d_in[16];
    const int* aei       = (const int*)d_in[17];

    int E  = in_sizes[16];
    int Nn = in_sizes[0] / 64;
    const int* srcp = aei;
    const int* dstp = aei + E;

    float* wsf = (float*)d_ws;
    int*   wsi = (int*)d_ws;

    size_t o = IB;
    int* modep  = wsi + o; o += 16;
    int* cnt    = wsi + o; o += Nn;      // cnt, hist, hcnt contiguous for k_zero
    int* hist   = wsi + o; o += 64;
    int* hcnt   = wsi + o; o += 64;
    int* offs   = wsi + o; o += Nn + 1;
    int* cursor = wsi + o; o += Nn;
    int* bsum   = wsi + o; o += 256;
    int* norder = wsi + o; o += Nn;
    int* perm   = wsi + o; o += E;
    o = (o + 3) & ~(size_t)3;
    u16* p2h = (u16*)(wsi + o); o += (size_t)Nn * 32;
    // total ws: ~ (IB + 1.0M + 1.6M)*4B ≈ 11 MB

    int NB = (Nn + 255) / 256;

    k_detect<<<1, 256, 0, stream>>>(atom_x, modep);
    k_zero<<<(Nn + 128 + 255) / 256, 256, 0, stream>>>(cnt, Nn + 128);
    k_prep<<<64, 256, 0, stream>>>(bond_emb, edge_w, edge_b, pre_w1, pre_b1, pre_w2, pre_b2,
                                   post_w1, post_b1, post_w2, post_b2, lin_w, lin_b, ln_g, ln_b,
                                   wsf, modep);
    k_count<<<(E + 255) / 256, 256, 0, stream>>>(dstp, cnt, E);
    k_scan1<<<NB, 256, 0, stream>>>(cnt, offs, bsum, Nn);
    k_scan2<<<1, 256, 0, stream>>>(bsum, NB);
    k_scan3<<<NB, 256, 0, stream>>>(offs, cnt, cursor, hist, bsum, Nn, E);
    k_order<<<NB, 256, 0, stream>>>(cnt, hist, hcnt, norder, Nn);
    k_scatter<<<(E + 255) / 256, 256, 0, stream>>>(dstp, cursor, perm, E);
    dim3 gn((Nn + 255) / 256, 4, 1);
    k_node<<<gn, 256, 0, stream>>>(atom_x, srcp, bond_x, offs, perm, norder, wsf, p2h, modep, Nn);
    k_final<<<(Nn + 15) / 16, 256, 0, stream>>>(atom_x, wsf, p2h, d_out, modep, Nn);
    k_marker<<<1, 64, 0, stream>>>(wsf, offs, perm, p2h, d_out, modep, Nn, E);
}

// Round 3
// 864.489 us; speedup vs baseline: 1.2745x; 1.2745x over previous
//
#include <hip/hip_runtime.h>
#include <cstdint>

typedef unsigned short u16;

#define AVG_LOG_F 1.4862356961977451f

// ---- workspace float-unit offsets (weights region) ----
#define OFF_W1   0      // pre_w1  fp32 [4][48][16]
#define OFF_W2   3072   // pre_w2  fp32 [4][16][16]
#define OFF_PW1  4096   // post_w1 fp32 [4][256][16]
#define OFF_PW2  20480  // post_w2 fp32 [4][16][16]
#define OFF_LW   21504  // lin_w   fp32 [64][64]
#define OFF_PB1  25600
#define OFF_PB2  25664
#define OFF_QB1  25728
#define OFF_QB2  25792
#define OFF_LB   25856
#define OFF_LG   25920
#define OFF_LBN  25984
#define OFF_ET   26048  // e_table fp32 [5][16]
#define IB       26176  // int region start (4B units); IB%4==0

__device__ __forceinline__ float bf2f(u16 u) {
    return __uint_as_float(((unsigned)u) << 16);
}
__device__ __forceinline__ u16 f2bf(float f) {
    unsigned u = __float_as_uint(f);
    u += 0x7fffu + ((u >> 16) & 1u);   // RNE
    return (u16)(u >> 16);
}
__device__ __forceinline__ float rdin(const void* p, int j, int mode) {
    if (mode == 0) return bf2f(((const u16*)p)[j]);
    return ((const float*)p)[j];
}
template <int MODE>
__device__ __forceinline__ void load16c(const void* p, long base, float* o) {
    if (MODE == 0) {
        const u16* q = (const u16*)p + base;
        uint4 a = *(const uint4*)q;
        uint4 b = *(const uint4*)(q + 8);
        o[0]  = __uint_as_float(a.x << 16); o[1]  = __uint_as_float(a.x & 0xffff0000u);
        o[2]  = __uint_as_float(a.y << 16); o[3]  = __uint_as_float(a.y & 0xffff0000u);
        o[4]  = __uint_as_float(a.z << 16); o[5]  = __uint_as_float(a.z & 0xffff0000u);
        o[6]  = __uint_as_float(a.w << 16); o[7]  = __uint_as_float(a.w & 0xffff0000u);
        o[8]  = __uint_as_float(b.x << 16); o[9]  = __uint_as_float(b.x & 0xffff0000u);
        o[10] = __uint_as_float(b.y << 16); o[11] = __uint_as_float(b.y & 0xffff0000u);
        o[12] = __uint_as_float(b.z << 16); o[13] = __uint_as_float(b.z & 0xffff0000u);
        o[14] = __uint_as_float(b.w << 16); o[15] = __uint_as_float(b.w & 0xffff0000u);
    } else {
        const float* q = (const float*)p + base;
        float4 a = *(const float4*)q;
        float4 b = *(const float4*)(q + 4);
        float4 c = *(const float4*)(q + 8);
        float4 d = *(const float4*)(q + 12);
        o[0]=a.x; o[1]=a.y; o[2]=a.z; o[3]=a.w;
        o[4]=b.x; o[5]=b.y; o[6]=b.z; o[7]=b.w;
        o[8]=c.x; o[9]=c.y; o[10]=c.z; o[11]=c.w;
        o[12]=d.x; o[13]=d.y; o[14]=d.z; o[15]=d.w;
    }
}

// ---------------- 0: zero counters + dtype detect (block 0) ----------------
__global__ __launch_bounds__(256) void k_zero_detect(int* p, int n, const void* ax, int* modep) {
    int i = blockIdx.x * 256 + threadIdx.x;
    if (i < n) p[i] = 0;
    if (blockIdx.x == 0) {
        __shared__ int csh;
        int tid = threadIdx.x;
        if (tid == 0) csh = 0;
        __syncthreads();
        unsigned v = ((const unsigned*)ax)[tid];
        unsigned lo = v & 0xffffu;
        int e = (int)((lo >> 7) & 0xff);
        int isbf = (lo == 0u) || (e >= 110 && e <= 140);
        atomicAdd(&csh, isbf);
        __syncthreads();
        if (tid == 0) modep[0] = (csh >= 192) ? 0 : 1;
    }
}

// ---------------- 1: weights -> fp32 in ws, edge table ----------------
__global__ __launch_bounds__(256) void k_prep(
    const void* bond_emb, const void* edge_w, const void* edge_b,
    const void* pre_w1, const void* pre_b1, const void* pre_w2, const void* pre_b2,
    const void* post_w1, const void* post_b1, const void* post_w2, const void* post_b2,
    const void* lin_w, const void* lin_b, const void* ln_g, const void* ln_b,
    float* wsf, const int* modep)
{
    int mode = modep[0];
    int gt = blockIdx.x * blockDim.x + threadIdx.x;
    int gs = gridDim.x * blockDim.x;
    for (int j = gt; j < 3072; j += gs)  wsf[OFF_W1 + j]  = rdin(pre_w1, j, mode);
    for (int j = gt; j < 1024; j += gs)  wsf[OFF_W2 + j]  = rdin(pre_w2, j, mode);
    for (int j = gt; j < 16384; j += gs) wsf[OFF_PW1 + j] = rdin(post_w1, j, mode);
    for (int j = gt; j < 1024; j += gs)  wsf[OFF_PW2 + j] = rdin(post_w2, j, mode);
    for (int j = gt; j < 4096; j += gs)  wsf[OFF_LW + j]  = rdin(lin_w, j, mode);
    for (int j = gt; j < 64; j += gs) {
        wsf[OFF_PB1 + j] = rdin(pre_b1, j, mode);
        wsf[OFF_PB2 + j] = rdin(pre_b2, j, mode);
        wsf[OFF_QB1 + j] = rdin(post_b1, j, mode);
        wsf[OFF_QB2 + j] = rdin(post_b2, j, mode);
        wsf[OFF_LB + j]  = rdin(lin_b, j, mode);
        wsf[OFF_LG + j]  = rdin(ln_g, j, mode);
        wsf[OFF_LBN + j] = rdin(ln_b, j, mode);
    }
    if (gt < 80) {
        int b = gt >> 4, f = gt & 15;
        float acc = rdin(edge_b, f, mode);
        for (int k = 0; k < 64; k++)
            acc = fmaf(rdin(bond_emb, b * 64 + k, mode), rdin(edge_w, k * 16 + f, mode), acc);
        wsf[OFF_ET + gt] = acc;
    }
}

// ---------------- 2: degree count ----------------
__global__ __launch_bounds__(256) void k_count(const int* __restrict__ dstp, int* __restrict__ cnt, int E) {
    int e = blockIdx.x * 256 + threadIdx.x;
    if (e < E) atomicAdd(&cnt[dstp[e]], 1);
}

// ---------------- 3a: per-256-chunk inclusive scan ----------------
__global__ __launch_bounds__(256) void k_scan1(const int* __restrict__ cnt, int* __restrict__ offs,
                                               int* __restrict__ bsum, int Nn) {
    __shared__ int sh[256];
    int tid = threadIdx.x;
    int i = blockIdx.x * 256 + tid;
    int v = (i < Nn) ? cnt[i] : 0;
    sh[tid] = v;
    __syncthreads();
    for (int o = 1; o < 256; o <<= 1) {
        int u = (tid >= o) ? sh[tid - o] : 0;
        __syncthreads();
        sh[tid] += u;
        __syncthreads();
    }
    if (i < Nn) offs[i] = sh[tid];
    if (tid == 255) bsum[blockIdx.x] = sh[255];
}

// ---------------- 3b: scan block sums (single block; NB <= 256) ----------------
__global__ __launch_bounds__(256) void k_scan2(int* __restrict__ bsum, int NB) {
    __shared__ int sh[256];
    int tid = threadIdx.x;
    int v = (tid < NB) ? bsum[tid] : 0;
    sh[tid] = v;
    __syncthreads();
    for (int o = 1; o < 256; o <<= 1) {
        int u = (tid >= o) ? sh[tid - o] : 0;
        __syncthreads();
        sh[tid] += u;
        __syncthreads();
    }
    if (tid < NB) bsum[tid] = sh[tid];
}

// ---------------- 3c: finalize exclusive offsets, cursor, degree hist ----------------
__global__ __launch_bounds__(256) void k_scan3(int* __restrict__ offs, const int* __restrict__ cnt,
                                               int* __restrict__ cursor, int* __restrict__ hist,
                                               const int* __restrict__ bsum, int Nn, int E) {
    int tid = threadIdx.x, b = blockIdx.x;
    int base = (b > 0) ? bsum[b - 1] : 0;
    int i = b * 256 + tid;
    if (i < Nn) {
        int c = cnt[i];
        int st = offs[i] - c + base;
        offs[i] = st;
        cursor[i] = st;
        atomicAdd(&hist[c < 63 ? c : 63], 1);
    }
    if (i == 0) offs[Nn] = E;
}

// ---------------- 4: degree-sorted node order (DESCENDING for tail balance) ----------------
__global__ __launch_bounds__(256) void k_order(const int* __restrict__ cnt, const int* __restrict__ hist,
                                               int* __restrict__ hcnt, int* __restrict__ norder, int Nn) {
    __shared__ int hbase[64];
    int tid = threadIdx.x;
    if (tid < 64) {
        int v = hist[tid];
        int orig = v;
        for (int o = 1; o < 64; o <<= 1) { int u = __shfl_up(v, o); if (tid >= o) v += u; }
        hbase[tid] = v - orig;
    }
    __syncthreads();
    int i = blockIdx.x * 256 + tid;
    if (i < Nn) {
        int c = cnt[i];
        int bin = c < 63 ? c : 63;
        int pos = hbase[bin] + atomicAdd(&hcnt[bin], 1);
        norder[Nn - 1 - pos] = i;   // heaviest first
    }
}

// ---------------- 5: CSR scatter with pre-gathered packed (src<<3|bond) ----------------
__global__ __launch_bounds__(256) void k_scatter(const int* __restrict__ dstp, const int* __restrict__ srcp,
                                                 const int* __restrict__ bondp, int* __restrict__ cursor,
                                                 int* __restrict__ pk, int E) {
    int e = blockIdx.x * 256 + threadIdx.x;
    if (e < E) {
        int pos = atomicAdd(&cursor[dstp[e]], 1);
        pk[pos] = (srcp[e] << 3) | (bondp[e] & 7);
    }
}

// ---------------- 6: fused messages + aggregation + post-MLP ----------------
__device__ __forceinline__ void statblk(const float a[16], const float* __restrict__ PW1, int blkbase,
                                        float sc1, float sc2, float p1[16]) {
#pragma unroll
    for (int f = 0; f < 16; f++) {
        float av = a[f];
#pragma unroll
        for (int g = 0; g < 16; g++) {
            float w = fmaf(sc2, PW1[(176 + blkbase + f) * 16 + g],
                     fmaf(sc1, PW1[(96 + blkbase + f) * 16 + g],
                               PW1[(16 + blkbase + f) * 16 + g]));
            p1[g] = fmaf(av, w, p1[g]);
        }
    }
}

template <int MODE>
__global__ __launch_bounds__(256, 2) void k_node(
    const void* __restrict__ ax, const int* __restrict__ pk,
    const int* __restrict__ offs, const int* __restrict__ norder,
    const float* __restrict__ wsf, u16* __restrict__ p2h, const int* __restrict__ modep, int Nn)
{
    if (modep[0] != MODE) return;      // wrong-dtype grid exits immediately
    int i = blockIdx.x * 256 + threadIdx.x;
    if (i >= Nn) return;
    int t = blockIdx.y;
    int n = norder[i];
    int start = offs[n];
    int deg = offs[n + 1] - start;

    const float* W1  = wsf + OFF_W1  + t * 768;
    const float* W2  = wsf + OFF_W2  + t * 256;
    const float* PW1 = wsf + OFF_PW1 + t * 4096;
    const float* PW2 = wsf + OFF_PW2 + t * 256;
    const float* PB1 = wsf + OFF_PB1 + t * 16;
    const float* PB2 = wsf + OFF_PB2 + t * 16;
    const float* QB1 = wsf + OFF_QB1 + t * 16;
    const float* QB2 = wsf + OFF_QB2 + t * 16;
    const float* ET  = wsf + OFF_ET;

    float xi[16];
    load16c<MODE>(ax, (long)n * 64 + t * 16, xi);

    float s[16], s2[16], mn[16], mx[16];
#pragma unroll
    for (int g = 0; g < 16; g++) { s[g] = 0.f; s2[g] = 0.f; mn[g] = 3.0e38f; mx[g] = -3.0e38f; }

    const int* pke = pk + start;
    for (int k = 0; k < deg; k++) {
        int v = pke[k];
        int sn = v >> 3;
        int bd = v & 7;
        float xj[16];
        load16c<MODE>(ax, (long)sn * 64 + t * 16, xj);
        float h1[16];
#pragma unroll
        for (int g = 0; g < 16; g++) h1[g] = PB1[g];
#pragma unroll
        for (int f = 0; f < 16; f++) {
            float a = xi[f], b = xj[f], c = ET[bd * 16 + f];
#pragma unroll
            for (int g = 0; g < 16; g++)
                h1[g] = fmaf(a, W1[f * 16 + g],
                        fmaf(b, W1[(16 + f) * 16 + g],
                        fmaf(c, W1[(32 + f) * 16 + g], h1[g])));
        }
#pragma unroll
        for (int f = 0; f < 16; f++) h1[f] = fmaxf(h1[f], 0.f);
#pragma unroll
        for (int g = 0; g < 16; g++) {
            float m = PB2[g];
#pragma unroll
            for (int f = 0; f < 16; f++) m = fmaf(h1[f], W2[f * 16 + g], m);
            s[g] += m;
            s2[g] = fmaf(m, m, s2[g]);
            mn[g] = fminf(mn[g], m);
            mx[g] = fmaxf(mx[g], m);
        }
    }

    if (deg == 0) {
#pragma unroll
        for (int g = 0; g < 16; g++) { mn[g] = 0.f; mx[g] = 0.f; }
    }
    float cf = (float)(deg > 0 ? deg : 1);
    float inv = 1.0f / cf;
    float mean[16], sd[16];
#pragma unroll
    for (int g = 0; g < 16; g++) {
        mean[g] = s[g] * inv;
        float m2 = s2[g] * inv;
        float v = m2 - mean[g] * mean[g];
        sd[g] = sqrtf(fmaxf(v, 0.f) + 1e-5f);
    }
    float ldv = logf(cf + 1.0f);
    float sc1 = ldv * (1.0f / AVG_LOG_F);
    float sc2 = AVG_LOG_F / ldv;

    float p1[16];
#pragma unroll
    for (int g = 0; g < 16; g++) p1[g] = QB1[g];
#pragma unroll
    for (int f = 0; f < 16; f++) {
        float a = xi[f];
#pragma unroll
        for (int g = 0; g < 16; g++) p1[g] = fmaf(a, PW1[f * 16 + g], p1[g]);
    }
    statblk(s,    PW1, 0,  sc1, sc2, p1);
    statblk(mean, PW1, 16, sc1, sc2, p1);
    statblk(mn,   PW1, 32, sc1, sc2, p1);
    statblk(mx,   PW1, 48, sc1, sc2, p1);
    statblk(sd,   PW1, 64, sc1, sc2, p1);
#pragma unroll
    for (int f = 0; f < 16; f++) p1[f] = fmaxf(p1[f], 0.f);

    float m[16];
#pragma unroll
    for (int g = 0; g < 16; g++) {
        float acc = QB2[g];
#pragma unroll
        for (int f = 0; f < 16; f++) acc = fmaf(p1[f], PW2[f * 16 + g], acc);
        m[g] = acc;
    }
    uint4 A, B;
    A.x = (unsigned)f2bf(m[0])  | ((unsigned)f2bf(m[1])  << 16);
    A.y = (unsigned)f2bf(m[2])  | ((unsigned)f2bf(m[3])  << 16);
    A.z = (unsigned)f2bf(m[4])  | ((unsigned)f2bf(m[5])  << 16);
    A.w = (unsigned)f2bf(m[6])  | ((unsigned)f2bf(m[7])  << 16);
    B.x = (unsigned)f2bf(m[8])  | ((unsigned)f2bf(m[9])  << 16);
    B.y = (unsigned)f2bf(m[10]) | ((unsigned)f2bf(m[11]) << 16);
    B.z = (unsigned)f2bf(m[12]) | ((unsigned)f2bf(m[13]) << 16);
    B.w = (unsigned)f2bf(m[14]) | ((unsigned)f2bf(m[15]) << 16);
    uint4* dst = (uint4*)(p2h + (long)n * 64 + t * 16);
    dst[0] = A;
    dst[1] = B;
}

// ---------------- 7: 64x64 linear + LayerNorm + ReLU + residual ----------------
__global__ __launch_bounds__(256) void k_final(
    const void* __restrict__ ax, const float* __restrict__ wsf,
    const u16* __restrict__ p2h, void* __restrict__ outp, const int* __restrict__ modep, int Nn)
{
    int tid = threadIdx.x;
    int wid = (blockIdx.x * 256 + tid) >> 6;
    int l = tid & 63;
    int mode = modep[0];
    int n0 = wid * 4;
    if (n0 >= Nn) return;
    const float* LW = wsf + OFF_LW;
    float lb = wsf[OFF_LB + l];
    const u16* r0 = p2h + (long)n0 * 64;
    float a0 = lb, a1 = lb, a2 = lb, a3 = lb;
#pragma unroll
    for (int f = 0; f < 64; f++) {
        float w = LW[f * 64 + l];
        a0 = fmaf(bf2f(r0[f]),       w, a0);
        a1 = fmaf(bf2f(r0[64 + f]),  w, a1);
        a2 = fmaf(bf2f(r0[128 + f]), w, a2);
        a3 = fmaf(bf2f(r0[192 + f]), w, a3);
    }
    float g = wsf[OFF_LG + l], be = wsf[OFF_LBN + l];
    float acc[4] = {a0, a1, a2, a3};
#pragma unroll
    for (int j = 0; j < 4; j++) {
        if (n0 + j >= Nn) break;
        float v = acc[j];
        float s1 = v, sq = v * v;
#pragma unroll
        for (int o = 1; o < 64; o <<= 1) { s1 += __shfl_xor(s1, o); sq += __shfl_xor(sq, o); }
        float mu = s1 * (1.0f / 64.0f);
        float var = sq * (1.0f / 64.0f) - mu * mu;
        float ln = (v - mu) * rsqrtf(var + 1e-5f) * g + be;
        long idx = (long)(n0 + j) * 64 + l;
        float res = rdin(ax, (int)idx, mode) + fmaxf(ln, 0.f);
        if (mode == 0) ((u16*)outp)[idx] = f2bf(res);
        else           ((float*)outp)[idx] = res;
    }
}

// ---------------- 8: diagnostic marker (no-op when healthy) ----------------
__global__ __launch_bounds__(64) void k_marker(
    const float* __restrict__ wsf, const int* __restrict__ offs, const int* __restrict__ pk,
    const u16* __restrict__ p2h, void* __restrict__ outp, const int* __restrict__ modep,
    int Nn, int E)
{
    if (threadIdx.x != 0 || blockIdx.x != 0) return;
    int code = 0;
    if (__float_as_uint(wsf[OFF_W1 + 5]) == 0xAAAAAAAAu) code |= 1;
    if (offs[Nn] != E) code |= 2;
    if (((const unsigned*)pk)[0] == 0xAAAAAAAAu &&
        ((const unsigned*)pk)[1] == 0xAAAAAAAAu) code |= 4;
    if (p2h[0] == 0xAAAAu && p2h[1] == 0xAAAAu &&
        p2h[2] == 0xAAAAu && p2h[3] == 0xAAAAu) code |= 8;
    if (code != 0) {
        float val = 1024.0f * (float)code;
        if (modep[0] == 0) ((u16*)outp)[0] = f2bf(val);
        else               ((float*)outp)[0] = val;
    }
}

extern "C" void kernel_launch(void* const* d_in, const int* in_sizes, int n_in,
                              void* d_out, int out_size, void* d_ws, size_t ws_size,
                              hipStream_t stream) {
    const void* atom_x   = d_in[0];
    const void* bond_emb = d_in[1];
    const void* edge_w   = d_in[2];
    const void* edge_b   = d_in[3];
    const void* pre_w1   = d_in[4];
    const void* pre_b1   = d_in[5];
    const void* pre_w2   = d_in[6];
    const void* pre_b2   = d_in[7];
    const void* post_w1  = d_in[8];
    const void* post_b1  = d_in[9];
    const void* post_w2  = d_in[10];
    const void* post_b2  = d_in[11];
    const void* lin_w    = d_in[12];
    const void* lin_b    = d_in[13];
    const void* ln_g     = d_in[14];
    const void* ln_b     = d_in[15];
    const int* bond_x    = (const int*)d_in[16];
    const int* aei       = (const int*)d_in[17];

    int E  = in_sizes[16];
    int Nn = in_sizes[0] / 64;
    const int* srcp = aei;
    const int* dstp = aei + E;

    float* wsf = (float*)d_ws;
    int*   wsi = (int*)d_ws;

    size_t o = IB;
    int* modep  = wsi + o; o += 16;
    int* cnt    = wsi + o; o += Nn;      // cnt, hist, hcnt contiguous for zeroing
    int* hist   = wsi + o; o += 64;
    int* hcnt   = wsi + o; o += 64;
    int* offs   = wsi + o; o += Nn + 1;
    int* cursor = wsi + o; o += Nn;
    int* bsum   = wsi + o; o += 256;
    int* norder = wsi + o; o += Nn;
    int* pk     = wsi + o; o += E;
    o = (o + 3) & ~(size_t)3;
    u16* p2h = (u16*)(wsi + o); o += (size_t)Nn * 32;

    int NB = (Nn + 255) / 256;

    k_zero_detect<<<(Nn + 128 + 255) / 256, 256, 0, stream>>>(cnt, Nn + 128, atom_x, modep);
    k_prep<<<64, 256, 0, stream>>>(bond_emb, edge_w, edge_b, pre_w1, pre_b1, pre_w2, pre_b2,
                                   post_w1, post_b1, post_w2, post_b2, lin_w, lin_b, ln_g, ln_b,
                                   wsf, modep);
    k_count<<<(E + 255) / 256, 256, 0, stream>>>(dstp, cnt, E);
    k_scan1<<<NB, 256, 0, stream>>>(cnt, offs, bsum, Nn);
    k_scan2<<<1, 256, 0, stream>>>(bsum, NB);
    k_scan3<<<NB, 256, 0, stream>>>(offs, cnt, cursor, hist, bsum, Nn, E);
    k_order<<<NB, 256, 0, stream>>>(cnt, hist, hcnt, norder, Nn);
    k_scatter<<<(E + 255) / 256, 256, 0, stream>>>(dstp, srcp, bond_x, cursor, pk, E);
    dim3 gn((Nn + 255) / 256, 4, 1);
    k_node<0><<<gn, 256, 0, stream>>>(atom_x, pk, offs, norder, wsf, p2h, modep, Nn);
    k_node<1><<<gn, 256, 0, stream>>>(atom_x, pk, offs, norder, wsf, p2h, modep, Nn);
    k_final<<<(Nn + 15) / 16, 256, 0, stream>>>(atom_x, wsf, p2h, d_out, modep, Nn);
    k_marker<<<1, 64, 0, stream>>>(wsf, offs, pk, p2h, d_out, modep, Nn, E);
}

// Round 6
// 805.034 us; speedup vs baseline: 1.3686x; 1.0739x over previous
//
#include <hip/hip_runtime.h>
#include <cstdint>

typedef unsigned short u16;

#define AVG_LOG_F 1.4862356961977451f

// ---- workspace float-unit offsets (weights region) ----
#define OFF_W1   0      // pre_w1  fp32 [4][48][16]
#define OFF_W2   3072   // pre_w2  fp32 [4][16][16]
#define OFF_PW1  4096   // post_w1 fp32 [4][256][16]
#define OFF_PW2  20480  // post_w2 fp32 [4][16][16]
#define OFF_LW   21504  // lin_w   fp32 [64][64]
#define OFF_PB1  25600
#define OFF_PB2  25664
#define OFF_QB1  25728
#define OFF_QB2  25792
#define OFF_LB   25856
#define OFF_LG   25920
#define OFF_LBN  25984
#define OFF_ET   26048  // e_table fp32 [5][16]
#define IB       26176  // int region start (4B units)

__device__ __forceinline__ float bf2f(u16 u) {
    return __uint_as_float(((unsigned)u) << 16);
}
__device__ __forceinline__ u16 f2bf(float f) {
    unsigned u = __float_as_uint(f);
    u += 0x7fffu + ((u >> 16) & 1u);   // RNE
    return (u16)(u >> 16);
}
__device__ __forceinline__ float rdin(const void* p, int j, int mode) {
    if (mode == 0) return bf2f(((const u16*)p)[j]);
    return ((const float*)p)[j];
}
template <int MODE>
__device__ __forceinline__ void load16c(const void* p, long base, float* o) {
    if (MODE == 0) {
        const u16* q = (const u16*)p + base;
        uint4 a = *(const uint4*)q;
        uint4 b = *(const uint4*)(q + 8);
        o[0]  = __uint_as_float(a.x << 16); o[1]  = __uint_as_float(a.x & 0xffff0000u);
        o[2]  = __uint_as_float(a.y << 16); o[3]  = __uint_as_float(a.y & 0xffff0000u);
        o[4]  = __uint_as_float(a.z << 16); o[5]  = __uint_as_float(a.z & 0xffff0000u);
        o[6]  = __uint_as_float(a.w << 16); o[7]  = __uint_as_float(a.w & 0xffff0000u);
        o[8]  = __uint_as_float(b.x << 16); o[9]  = __uint_as_float(b.x & 0xffff0000u);
        o[10] = __uint_as_float(b.y << 16); o[11] = __uint_as_float(b.y & 0xffff0000u);
        o[12] = __uint_as_float(b.z << 16); o[13] = __uint_as_float(b.z & 0xffff0000u);
        o[14] = __uint_as_float(b.w << 16); o[15] = __uint_as_float(b.w & 0xffff0000u);
    } else {
        const float* q = (const float*)p + base;
        float4 a = *(const float4*)q;
        float4 b = *(const float4*)(q + 4);
        float4 c = *(const float4*)(q + 8);
        float4 d = *(const float4*)(q + 12);
        o[0]=a.x; o[1]=a.y; o[2]=a.z; o[3]=a.w;
        o[4]=b.x; o[5]=b.y; o[6]=b.z; o[7]=b.w;
        o[8]=c.x; o[9]=c.y; o[10]=c.z; o[11]=c.w;
        o[12]=d.x; o[13]=d.y; o[14]=d.z; o[15]=d.w;
    }
}

// ---------------- 0: zero counters + dtype detect (block 0) ----------------
__global__ __launch_bounds__(256) void k_zero_detect(int* p, int n, const void* ax, int* modep) {
    int i = blockIdx.x * 256 + threadIdx.x;
    if (i < n) p[i] = 0;
    if (blockIdx.x == 0) {
        __shared__ int csh;
        int tid = threadIdx.x;
        if (tid == 0) csh = 0;
        __syncthreads();
        unsigned v = ((const unsigned*)ax)[tid];
        unsigned lo = v & 0xffffu;
        int e = (int)((lo >> 7) & 0xff);
        int isbf = (lo == 0u) || (e >= 110 && e <= 140);
        atomicAdd(&csh, isbf);
        __syncthreads();
        if (tid == 0) modep[0] = (csh >= 192) ? 0 : 1;
    }
}

// ---------------- 1: weights -> fp32 in ws, edge table ----------------
__global__ __launch_bounds__(256) void k_prep(
    const void* bond_emb, const void* edge_w, const void* edge_b,
    const void* pre_w1, const void* pre_b1, const void* pre_w2, const void* pre_b2,
    const void* post_w1, const void* post_b1, const void* post_w2, const void* post_b2,
    const void* lin_w, const void* lin_b, const void* ln_g, const void* ln_b,
    float* wsf, const int* modep)
{
    int mode = modep[0];
    int gt = blockIdx.x * blockDim.x + threadIdx.x;
    int gs = gridDim.x * blockDim.x;
    for (int j = gt; j < 3072; j += gs)  wsf[OFF_W1 + j]  = rdin(pre_w1, j, mode);
    for (int j = gt; j < 1024; j += gs)  wsf[OFF_W2 + j]  = rdin(pre_w2, j, mode);
    for (int j = gt; j < 16384; j += gs) wsf[OFF_PW1 + j] = rdin(post_w1, j, mode);
    for (int j = gt; j < 1024; j += gs)  wsf[OFF_PW2 + j] = rdin(post_w2, j, mode);
    for (int j = gt; j < 4096; j += gs)  wsf[OFF_LW + j]  = rdin(lin_w, j, mode);
    for (int j = gt; j < 64; j += gs) {
        wsf[OFF_PB1 + j] = rdin(pre_b1, j, mode);
        wsf[OFF_PB2 + j] = rdin(pre_b2, j, mode);
        wsf[OFF_QB1 + j] = rdin(post_b1, j, mode);
        wsf[OFF_QB2 + j] = rdin(post_b2, j, mode);
        wsf[OFF_LB + j]  = rdin(lin_b, j, mode);
        wsf[OFF_LG + j]  = rdin(ln_g, j, mode);
        wsf[OFF_LBN + j] = rdin(ln_b, j, mode);
    }
    if (gt < 80) {
        int b = gt >> 4, f = gt & 15;
        float acc = rdin(edge_b, f, mode);
        for (int k = 0; k < 64; k++)
            acc = fmaf(rdin(bond_emb, b * 64 + k, mode), rdin(edge_w, k * 16 + f, mode), acc);
        wsf[OFF_ET + gt] = acc;
    }
}

// ---------------- 2: degree count ----------------
__global__ __launch_bounds__(256) void k_count(const int* __restrict__ dstp, int* __restrict__ cnt, int E) {
    int e = blockIdx.x * 256 + threadIdx.x;
    if (e < E) atomicAdd(&cnt[dstp[e]], 1);
}

// ---------------- 3a: per-256-chunk inclusive scan ----------------
__global__ __launch_bounds__(256) void k_scan1(const int* __restrict__ cnt, int* __restrict__ offs,
                                               int* __restrict__ bsum, int Nn) {
    __shared__ int sh[256];
    int tid = threadIdx.x;
    int i = blockIdx.x * 256 + tid;
    int v = (i < Nn) ? cnt[i] : 0;
    sh[tid] = v;
    __syncthreads();
    for (int o = 1; o < 256; o <<= 1) {
        int u = (tid >= o) ? sh[tid - o] : 0;
        __syncthreads();
        sh[tid] += u;
        __syncthreads();
    }
    if (i < Nn) offs[i] = sh[tid];
    if (tid == 255) bsum[blockIdx.x] = sh[255];
}

// ---------------- 3b: scan block sums (single block; NB <= 256) ----------------
__global__ __launch_bounds__(256) void k_scan2(int* __restrict__ bsum, int NB) {
    __shared__ int sh[256];
    int tid = threadIdx.x;
    int v = (tid < NB) ? bsum[tid] : 0;
    sh[tid] = v;
    __syncthreads();
    for (int o = 1; o < 256; o <<= 1) {
        int u = (tid >= o) ? sh[tid - o] : 0;
        __syncthreads();
        sh[tid] += u;
        __syncthreads();
    }
    if (tid < NB) bsum[tid] = sh[tid];
}

// ---------------- 3c: finalize exclusive offsets, cursor, degree hist ----------------
__global__ __launch_bounds__(256) void k_scan3(int* __restrict__ offs, const int* __restrict__ cnt,
                                               int* __restrict__ cursor, int* __restrict__ hist,
                                               const int* __restrict__ bsum, int Nn, int E) {
    int tid = threadIdx.x, b = blockIdx.x;
    int base = (b > 0) ? bsum[b - 1] : 0;
    int i = b * 256 + tid;
    if (i < Nn) {
        int c = cnt[i];
        int st = offs[i] - c + base;
        offs[i] = st;
        cursor[i] = st;
        atomicAdd(&hist[c < 63 ? c : 63], 1);
    }
    if (i == 0) offs[Nn] = E;
}

// ---------------- 4: degree-sorted node order (DESCENDING for tail balance) ----------------
__global__ __launch_bounds__(256) void k_order(const int* __restrict__ cnt, const int* __restrict__ hist,
                                               int* __restrict__ hcnt, int* __restrict__ norder, int Nn) {
    __shared__ int hbase[64];
    int tid = threadIdx.x;
    if (tid < 64) {
        int v = hist[tid];
        int orig = v;
        for (int o = 1; o < 64; o <<= 1) { int u = __shfl_up(v, o); if (tid >= o) v += u; }
        hbase[tid] = v - orig;
    }
    __syncthreads();
    int i = blockIdx.x * 256 + tid;
    if (i < Nn) {
        int c = cnt[i];
        int bin = c < 63 ? c : 63;
        int pos = hbase[bin] + atomicAdd(&hcnt[bin], 1);
        norder[Nn - 1 - pos] = i;   // heaviest first
    }
}

// ---------------- 5: CSR scatter with pre-gathered packed (src<<3|bond) ----------------
__global__ __launch_bounds__(256) void k_scatter(const int* __restrict__ dstp, const int* __restrict__ srcp,
                                                 const int* __restrict__ bondp, int* __restrict__ cursor,
                                                 int* __restrict__ pk, int E) {
    int e = blockIdx.x * 256 + threadIdx.x;
    if (e < E) {
        int pos = atomicAdd(&cursor[dstp[e]], 1);
        pk[pos] = (srcp[e] << 3) | (bondp[e] & 7);
    }
}

// ---------------- 6: lane-cooperative node kernel: 16 lanes per (node, tower) ----------------
// lane g owns output channel g; W1/W2/PW2 columns live in VGPRs for the thread's lifetime.
template <int MODE>
__global__ __launch_bounds__(256, 4) void k_node_coop(
    const void* __restrict__ ax, const int* __restrict__ pk,
    const int* __restrict__ offs, const int* __restrict__ norder,
    const float* __restrict__ wsf, u16* __restrict__ p2h,
    const int* __restrict__ modep, int* __restrict__ flags, int Nn)
{
    if (modep[0] != MODE) return;      // wrong-dtype grid exits immediately
    if (threadIdx.x == 0 && blockIdx.x == 0 && blockIdx.y == 0) flags[0] = 1;
    const int t = blockIdx.y;
    const int lane = threadIdx.x & 63;
    const int g = lane & 15;
    const int base = lane & 48;                        // first lane of this 16-lane slot
    const int gslot = (blockIdx.x * 256 + threadIdx.x) >> 4;
    if (gslot >= Nn) return;

    const float* W1  = wsf + OFF_W1  + t * 768;
    const float* W2  = wsf + OFF_W2  + t * 256;
    const float* PW1 = wsf + OFF_PW1 + t * 4096;
    const float* PW2 = wsf + OFF_PW2 + t * 256;
    const float* ET  = wsf + OFF_ET;

    float w1xj[16], w2c[16], pw2c[16];
#pragma unroll
    for (int f = 0; f < 16; f++) {
        w1xj[f] = W1[(16 + f) * 16 + g];
        w2c[f]  = W2[f * 16 + g];
        pw2c[f] = PW2[f * 16 + g];
    }
    float pb1g = wsf[OFF_PB1 + t * 16 + g];
    float pb2g = wsf[OFF_PB2 + t * 16 + g];
    float qb1g = wsf[OFF_QB1 + t * 16 + g];
    float qb2g = wsf[OFF_QB2 + t * 16 + g];
    float eW[5];
#pragma unroll
    for (int b = 0; b < 5; b++) {
        float acc = pb1g;
#pragma unroll
        for (int f = 0; f < 16; f++)
            acc = fmaf(ET[b * 16 + f], W1[(32 + f) * 16 + g], acc);
        eW[b] = acc;
    }

    int n = norder[gslot];
    int start = offs[n];
    int deg = offs[n + 1] - start;

    float xi[16];
    load16c<MODE>(ax, (long)n * 64 + t * 16, xi);
    float xiW = 0.f;
#pragma unroll
    for (int f = 0; f < 16; f++) xiW = fmaf(xi[f], W1[f * 16 + g], xiW);

    float s = 0.f, s2 = 0.f, mn = 3.0e38f, mx = -3.0e38f;
    const int* pke = pk + start;
    for (int k = 0; k < deg; k++) {
        int v = pke[k];
        int sn = v >> 3, bd = v & 7;
        float xj[16];
        load16c<MODE>(ax, (long)sn * 64 + t * 16, xj);
        float h = xiW + ((bd == 0) ? eW[0] : (bd == 1) ? eW[1] : (bd == 2) ? eW[2]
                          : (bd == 3) ? eW[3] : eW[4]);
#pragma unroll
        for (int f = 0; f < 16; f++) h = fmaf(xj[f], w1xj[f], h);
        h = fmaxf(h, 0.f);
        float m = pb2g;
#pragma unroll
        for (int f = 0; f < 16; f++) {
            float hf = __shfl(h, base + f, 64);
            m = fmaf(hf, w2c[f], m);
        }
        s += m;
        s2 = fmaf(m, m, s2);
        mn = fminf(mn, m);
        mx = fmaxf(mx, m);
    }

    if (deg == 0) { mn = 0.f; mx = 0.f; }
    float cf = (float)(deg > 0 ? deg : 1);
    float inv = 1.0f / cf;
    float mean = s * inv;
    float var = s2 * inv - mean * mean;
    float sd = sqrtf(fmaxf(var, 0.f) + 1e-5f);
    float ldv = logf(cf + 1.0f);
    float sc1 = ldv * (1.0f / AVG_LOG_F);
    float sc2 = AVG_LOG_F / ldv;

    float p1 = qb1g;
#pragma unroll
    for (int f = 0; f < 16; f++) p1 = fmaf(xi[f], PW1[f * 16 + g], p1);
    float aggv[5] = {s, mean, mn, mx, sd};
#pragma unroll
    for (int a = 0; a < 5; a++) {
        float av = aggv[a];
        int rb = 16 + a * 16;
#pragma unroll
        for (int f = 0; f < 16; f++) {
            float af = __shfl(av, base + f, 64);
            float w = fmaf(sc2, PW1[(rb + 160 + f) * 16 + g],
                      fmaf(sc1, PW1[(rb + 80 + f) * 16 + g],
                                PW1[(rb + f) * 16 + g]));
            p1 = fmaf(af, w, p1);
        }
    }
    p1 = fmaxf(p1, 0.f);
    float m2 = qb2g;
#pragma unroll
    for (int f = 0; f < 16; f++) {
        float pf = __shfl(p1, base + f, 64);
        m2 = fmaf(pf, pw2c[f], m2);
    }
    p2h[(long)n * 64 + t * 16 + g] = f2bf(m2);
}

// ---------------- 7: 64x64 linear + LayerNorm + ReLU + residual ----------------
__global__ __launch_bounds__(256) void k_final(
    const void* __restrict__ ax, const float* __restrict__ wsf,
    const u16* __restrict__ p2h, void* __restrict__ outp, const int* __restrict__ modep,
    int* __restrict__ flags, int Nn)
{
    int tid = threadIdx.x;
    if (tid == 0 && blockIdx.x == 0) flags[1] = 1;
    int wid = (blockIdx.x * 256 + tid) >> 6;
    int l = tid & 63;
    int mode = modep[0];
    int n0 = wid * 4;
    if (n0 >= Nn) return;
    const float* LW = wsf + OFF_LW;
    float lb = wsf[OFF_LB + l];
    const u16* r0 = p2h + (long)n0 * 64;
    float a0 = lb, a1 = lb, a2 = lb, a3 = lb;
#pragma unroll
    for (int f = 0; f < 64; f++) {
        float w = LW[f * 64 + l];
        a0 = fmaf(bf2f(r0[f]),       w, a0);
        a1 = fmaf(bf2f(r0[64 + f]),  w, a1);
        a2 = fmaf(bf2f(r0[128 + f]), w, a2);
        a3 = fmaf(bf2f(r0[192 + f]), w, a3);
    }
    float g = wsf[OFF_LG + l], be = wsf[OFF_LBN + l];
    float acc[4] = {a0, a1, a2, a3};
#pragma unroll
    for (int j = 0; j < 4; j++) {
        if (n0 + j >= Nn) break;
        float v = acc[j];
        float s1 = v, sq = v * v;
#pragma unroll
        for (int o = 1; o < 64; o <<= 1) { s1 += __shfl_xor(s1, o); sq += __shfl_xor(sq, o); }
        float mu = s1 * (1.0f / 64.0f);
        float var = sq * (1.0f / 64.0f) - mu * mu;
        float ln = (v - mu) * rsqrtf(var + 1e-5f) * g + be;
        long idx = (long)(n0 + j) * 64 + l;
        float res = rdin(ax, (int)idx, mode) + fmaxf(ln, 0.f);
        if (mode == 0) ((u16*)outp)[idx] = f2bf(res);
        else           ((float*)outp)[idx] = res;
    }
}

// ---------------- 8: diagnostic marker (no-op when healthy) ----------------
__global__ __launch_bounds__(64) void k_marker(
    const float* __restrict__ wsf, const int* __restrict__ offs, const int* __restrict__ pk,
    const u16* __restrict__ p2h, void* __restrict__ outp, const int* __restrict__ modep,
    const int* __restrict__ flags, int Nn, int E)
{
    if (threadIdx.x != 0 || blockIdx.x != 0) return;
    int code = 0;
    if (__float_as_uint(wsf[OFF_W1 + 5]) == 0xAAAAAAAAu) code |= 1;     // k_prep dead
    if (offs[Nn] != E) code |= 2;                                       // scan dead
    if (((const unsigned*)pk)[0] == 0xAAAAAAAAu &&
        ((const unsigned*)pk)[1] == 0xAAAAAAAAu) code |= 4;             // scatter dead
    if (p2h[0] == 0xAAAAu && p2h[1] == 0xAAAAu &&
        p2h[2] == 0xAAAAu && p2h[3] == 0xAAAAu) code |= 8;              // p2h head unwritten
    long tl = (long)Nn * 64 - 4;
    if (p2h[tl] == 0xAAAAu && p2h[tl+1] == 0xAAAAu &&
        p2h[tl+2] == 0xAAAAu && p2h[tl+3] == 0xAAAAu) code |= 16;       // p2h tail unwritten
    if (flags[0] == 0) code |= 32;                                      // k_node never entered
    if (flags[1] == 0) code |= 64;                                      // k_final never entered
    if (code != 0) {
        float val = 1024.0f * (float)code;
        if (modep[0] == 0) ((u16*)outp)[0] = f2bf(val);
        else               ((float*)outp)[0] = val;
    }
}

extern "C" void kernel_launch(void* const* d_in, const int* in_sizes, int n_in,
                              void* d_out, int out_size, void* d_ws, size_t ws_size,
                              hipStream_t stream) {
    const void* atom_x   = d_in[0];
    const void* bond_emb = d_in[1];
    const void* edge_w   = d_in[2];
    const void* edge_b   = d_in[3];
    const void* pre_w1   = d_in[4];
    const void* pre_b1   = d_in[5];
    const void* pre_w2   = d_in[6];
    const void* pre_b2   = d_in[7];
    const void* post_w1  = d_in[8];
    const void* post_b1  = d_in[9];
    const void* post_w2  = d_in[10];
    const void* post_b2  = d_in[11];
    const void* lin_w    = d_in[12];
    const void* lin_b    = d_in[13];
    const void* ln_g     = d_in[14];
    const void* ln_b     = d_in[15];
    const int* bond_x    = (const int*)d_in[16];
    const int* aei       = (const int*)d_in[17];

    int E  = in_sizes[16];
    int Nn = in_sizes[0] / 64;
    const int* srcp = aei;
    const int* dstp = aei + E;

    float* wsf = (float*)d_ws;
    int*   wsi = (int*)d_ws;

    size_t o = IB;
    int* modep  = wsi + o; o += 16;
    int* cnt    = wsi + o; o += Nn;      // cnt, hist, hcnt, flags contiguous for zeroing
    int* hist   = wsi + o; o += 64;
    int* hcnt   = wsi + o; o += 64;
    int* flags  = wsi + o; o += 64;
    int* offs   = wsi + o; o += Nn + 1;
    int* cursor = wsi + o; o += Nn;
    int* bsum   = wsi + o; o += 256;
    int* norder = wsi + o; o += Nn;
    int* pk     = wsi + o; o += E;
    o = (o + 3) & ~(size_t)3;
    u16* p2h = (u16*)(wsi + o); o += (size_t)Nn * 32;

    int NB = (Nn + 255) / 256;

    k_zero_detect<<<(Nn + 192 + 255) / 256, 256, 0, stream>>>(cnt, Nn + 192, atom_x, modep);
    k_prep<<<64, 256, 0, stream>>>(bond_emb, edge_w, edge_b, pre_w1, pre_b1, pre_w2, pre_b2,
                                   post_w1, post_b1, post_w2, post_b2, lin_w, lin_b, ln_g, ln_b,
                                   wsf, modep);
    k_count<<<(E + 255) / 256, 256, 0, stream>>>(dstp, cnt, E);
    k_scan1<<<NB, 256, 0, stream>>>(cnt, offs, bsum, Nn);
    k_scan2<<<1, 256, 0, stream>>>(bsum, NB);
    k_scan3<<<NB, 256, 0, stream>>>(offs, cnt, cursor, hist, bsum, Nn, E);
    k_order<<<NB, 256, 0, stream>>>(cnt, hist, hcnt, norder, Nn);
    k_scatter<<<(E + 255) / 256, 256, 0, stream>>>(dstp, srcp, bond_x, cursor, pk, E);
    dim3 gc((Nn * 16 + 255) / 256, 4, 1);
    k_node_coop<0><<<gc, 256, 0, stream>>>(atom_x, pk, offs, norder, wsf, p2h, modep, flags, Nn);
    k_node_coop<1><<<gc, 256, 0, stream>>>(atom_x, pk, offs, norder, wsf, p2h, modep, flags, Nn);
    k_final<<<(Nn + 15) / 16, 256, 0, stream>>>(atom_x, wsf, p2h, d_out, modep, flags, Nn);
    k_marker<<<1, 64, 0, stream>>>(wsf, offs, pk, p2h, d_out, modep, flags, Nn, E);
}

// Round 7
// 456.698 us; speedup vs baseline: 2.4125x; 1.7627x over previous
//
#include <hip/hip_runtime.h>
#include <cstdint>

typedef unsigned short u16;

#define AVG_LOG_F 1.4862356961977451f
#define MAXD 64

// ---- workspace float-unit offsets (weights region) ----
#define OFF_W1   0      // pre_w1  fp32 [4][48][16]
#define OFF_W2   3072   // pre_w2  fp32 [4][16][16]
#define OFF_PW1  4096   // post_w1 fp32 [4][256][16]
#define OFF_PW2  20480  // post_w2 fp32 [4][16][16]
#define OFF_LW   21504  // lin_w   fp32 [64][64]
#define OFF_PB1  25600
#define OFF_PB2  25664
#define OFF_QB1  25728
#define OFF_QB2  25792
#define OFF_LB   25856
#define OFF_LG   25920
#define OFF_LBN  25984
#define OFF_ET   26048  // e_table fp32 [5][16]
#define IB       26176  // int region start (4B units)

__device__ __forceinline__ float bf2f(u16 u) {
    return __uint_as_float(((unsigned)u) << 16);
}
__device__ __forceinline__ u16 f2bf(float f) {
    unsigned u = __float_as_uint(f);
    u += 0x7fffu + ((u >> 16) & 1u);
    return (u16)(u >> 16);
}
__device__ __forceinline__ float rdin(const void* p, int j, int mode) {
    if (mode == 0) return bf2f(((const u16*)p)[j]);
    return ((const float*)p)[j];
}
template <int MODE>
__device__ __forceinline__ void load16c(const void* p, long base, float* o) {
    if (MODE == 0) {
        const u16* q = (const u16*)p + base;
        uint4 a = *(const uint4*)q;
        uint4 b = *(const uint4*)(q + 8);
        o[0]  = __uint_as_float(a.x << 16); o[1]  = __uint_as_float(a.x & 0xffff0000u);
        o[2]  = __uint_as_float(a.y << 16); o[3]  = __uint_as_float(a.y & 0xffff0000u);
        o[4]  = __uint_as_float(a.z << 16); o[5]  = __uint_as_float(a.z & 0xffff0000u);
        o[6]  = __uint_as_float(a.w << 16); o[7]  = __uint_as_float(a.w & 0xffff0000u);
        o[8]  = __uint_as_float(b.x << 16); o[9]  = __uint_as_float(b.x & 0xffff0000u);
        o[10] = __uint_as_float(b.y << 16); o[11] = __uint_as_float(b.y & 0xffff0000u);
        o[12] = __uint_as_float(b.z << 16); o[13] = __uint_as_float(b.z & 0xffff0000u);
        o[14] = __uint_as_float(b.w << 16); o[15] = __uint_as_float(b.w & 0xffff0000u);
    } else {
        const float* q = (const float*)p + base;
        float4 a = *(const float4*)q;
        float4 b = *(const float4*)(q + 4);
        float4 c = *(const float4*)(q + 8);
        float4 d = *(const float4*)(q + 12);
        o[0]=a.x; o[1]=a.y; o[2]=a.z; o[3]=a.w;
        o[4]=b.x; o[5]=b.y; o[6]=b.z; o[7]=b.w;
        o[8]=c.x; o[9]=c.y; o[10]=c.z; o[11]=c.w;
        o[12]=d.x; o[13]=d.y; o[14]=d.z; o[15]=d.w;
    }
}

// ---------------- 1: init: detect dtype, zero cnt/flags, weights -> fp32, edge table --------
__global__ __launch_bounds__(256) void k_init(
    const void* bond_emb, const void* edge_w, const void* edge_b,
    const void* pre_w1, const void* pre_b1, const void* pre_w2, const void* pre_b2,
    const void* post_w1, const void* post_b1, const void* post_w2, const void* post_b2,
    const void* lin_w, const void* lin_b, const void* ln_g, const void* ln_b,
    const void* ax, float* wsf, int* cnt, int* modep, int* flags, int Nn)
{
    __shared__ int csh;
    int tid = threadIdx.x;
    if (tid == 0) csh = 0;
    __syncthreads();
    {
        unsigned v = ((const unsigned*)ax)[tid];
        unsigned lo = v & 0xffffu;
        int e = (int)((lo >> 7) & 0xff);
        int isbf = (lo == 0u) || (e >= 110 && e <= 140);
        atomicAdd(&csh, isbf);
    }
    __syncthreads();
    int mode = (csh >= 192) ? 0 : 1;

    int gt = blockIdx.x * 256 + tid;
    int gs = gridDim.x * 256;
    if (gt < Nn) cnt[gt] = 0;
    if (blockIdx.x == 0 && tid == 0) { modep[0] = mode; flags[0] = 0; flags[1] = 0; }

    for (int j = gt; j < 3072; j += gs)  wsf[OFF_W1 + j]  = rdin(pre_w1, j, mode);
    for (int j = gt; j < 1024; j += gs)  wsf[OFF_W2 + j]  = rdin(pre_w2, j, mode);
    for (int j = gt; j < 16384; j += gs) wsf[OFF_PW1 + j] = rdin(post_w1, j, mode);
    for (int j = gt; j < 1024; j += gs)  wsf[OFF_PW2 + j] = rdin(post_w2, j, mode);
    for (int j = gt; j < 4096; j += gs)  wsf[OFF_LW + j]  = rdin(lin_w, j, mode);
    for (int j = gt; j < 64; j += gs) {
        wsf[OFF_PB1 + j] = rdin(pre_b1, j, mode);
        wsf[OFF_PB2 + j] = rdin(pre_b2, j, mode);
        wsf[OFF_QB1 + j] = rdin(post_b1, j, mode);
        wsf[OFF_QB2 + j] = rdin(post_b2, j, mode);
        wsf[OFF_LB + j]  = rdin(lin_b, j, mode);
        wsf[OFF_LG + j]  = rdin(ln_g, j, mode);
        wsf[OFF_LBN + j] = rdin(ln_b, j, mode);
    }
    if (gt < 80) {
        int b = gt >> 4, f = gt & 15;
        float acc = rdin(edge_b, f, mode);
        for (int k = 0; k < 64; k++)
            acc = fmaf(rdin(bond_emb, b * 64 + k, mode), rdin(edge_w, k * 16 + f, mode), acc);
        wsf[OFF_ET + gt] = acc;
    }
}

// ---------------- 2: fused count+scatter into fixed-stride buckets ----------------
__global__ __launch_bounds__(256) void k_scatter(
    const int* __restrict__ dstp, const int* __restrict__ srcp, const int* __restrict__ bondp,
    int* __restrict__ cnt, int* __restrict__ pk, int E)
{
    int e = blockIdx.x * 256 + threadIdx.x;
    if (e < E) {
        int d = dstp[e];
        int pos = atomicAdd(&cnt[d], 1);
        if (pos < MAXD) pk[d * MAXD + pos] = (srcp[e] << 3) | (bondp[e] & 7);
    }
}

// ---------------- 3: wave-per-node fused kernel (64 lanes = 4 towers x 16 channels) --------
template <int MODE>
__global__ __launch_bounds__(256, 4) void k_node(
    const void* __restrict__ ax, const int* __restrict__ pk, const int* __restrict__ cnt,
    const float* __restrict__ wsf, float* __restrict__ p2f,
    const int* __restrict__ modep, int* __restrict__ flags, int Nn)
{
    if (modep[0] != MODE) return;
    if (threadIdx.x == 0 && blockIdx.x == 0) flags[0] = 1;
    __shared__ float hb[4][16][64];
    const int w = threadIdx.x >> 6;
    const int l = threadIdx.x & 63;
    const int t = l >> 4;
    const int g = l & 15;
    const int n = blockIdx.x * 4 + w;
    if (n >= Nn) return;

    const float* W1  = wsf + OFF_W1  + t * 768;
    const float* W2  = wsf + OFF_W2  + t * 256;
    const float* PW1 = wsf + OFF_PW1 + t * 4096;
    const float* PW2 = wsf + OFF_PW2 + t * 256;
    const float* ET  = wsf + OFF_ET;

    // thread-lifetime weight columns
    float w1xj[16], w2c[16], pw2c[16];
#pragma unroll
    for (int f = 0; f < 16; f++) {
        w1xj[f] = W1[(16 + f) * 16 + g];
        w2c[f]  = W2[f * 16 + g];
        pw2c[f] = PW2[f * 16 + g];
    }
    float pb1g = wsf[OFF_PB1 + t * 16 + g];
    float pb2g = wsf[OFF_PB2 + t * 16 + g];
    float qb1g = wsf[OFF_QB1 + t * 16 + g];
    float qb2g = wsf[OFF_QB2 + t * 16 + g];
    float eW0, eW1, eW2, eW3, eW4;
    {
        float a0 = pb1g, a1 = pb1g, a2 = pb1g, a3 = pb1g, a4 = pb1g;
#pragma unroll
        for (int f = 0; f < 16; f++) {
            float wc = W1[(32 + f) * 16 + g];
            a0 = fmaf(ET[0 * 16 + f], wc, a0);
            a1 = fmaf(ET[1 * 16 + f], wc, a1);
            a2 = fmaf(ET[2 * 16 + f], wc, a2);
            a3 = fmaf(ET[3 * 16 + f], wc, a3);
            a4 = fmaf(ET[4 * 16 + f], wc, a4);
        }
        eW0 = a0; eW1 = a1; eW2 = a2; eW3 = a3; eW4 = a4;
    }

    int deg = cnt[n];
    if (deg > MAXD) deg = MAXD;
    const int* pkrow = pk + n * MAXD;

    float xi[16];
    load16c<MODE>(ax, (long)n * 64 + t * 16, xi);
    float xiW = 0.f;
#pragma unroll
    for (int f = 0; f < 16; f++) xiW = fmaf(xi[f], W1[f * 16 + g], xiW);

    float s = 0.f, s2 = 0.f, mn = 3.0e38f, mx = -3.0e38f;

    for (int kb = 0; kb < deg; kb += 16) {
        int B = deg - kb; if (B > 16) B = 16;
        int pkv = (l < B) ? pkrow[kb + l] : 0;

        auto phaseA = [&](int k) {
            int v = __shfl(pkv, k, 64);
            int sn = v >> 3, bd = v & 7;
            float xj[16];
            load16c<MODE>(ax, (long)sn * 64 + t * 16, xj);
            float h = xiW + ((bd == 0) ? eW0 : (bd == 1) ? eW1 : (bd == 2) ? eW2
                              : (bd == 3) ? eW3 : eW4);
#pragma unroll
            for (int f = 0; f < 16; f++) h = fmaf(xj[f], w1xj[f], h);
            hb[w][k][l] = fmaxf(h, 0.f);
        };
        auto phaseB = [&](int k) {
            const float4* hp = (const float4*)&hb[w][k][t * 16];
            float4 h0 = hp[0], h1 = hp[1], h2 = hp[2], h3 = hp[3];
            float m = pb2g;
            m = fmaf(h0.x, w2c[0],  m); m = fmaf(h0.y, w2c[1],  m);
            m = fmaf(h0.z, w2c[2],  m); m = fmaf(h0.w, w2c[3],  m);
            m = fmaf(h1.x, w2c[4],  m); m = fmaf(h1.y, w2c[5],  m);
            m = fmaf(h1.z, w2c[6],  m); m = fmaf(h1.w, w2c[7],  m);
            m = fmaf(h2.x, w2c[8],  m); m = fmaf(h2.y, w2c[9],  m);
            m = fmaf(h2.z, w2c[10], m); m = fmaf(h2.w, w2c[11], m);
            m = fmaf(h3.x, w2c[12], m); m = fmaf(h3.y, w2c[13], m);
            m = fmaf(h3.z, w2c[14], m); m = fmaf(h3.w, w2c[15], m);
            s += m;
            s2 = fmaf(m, m, s2);
            mn = fminf(mn, m);
            mx = fmaxf(mx, m);
        };
        if (B == 16) {
#pragma unroll 4
            for (int k = 0; k < 16; k++) phaseA(k);
#pragma unroll 4
            for (int k = 0; k < 16; k++) phaseB(k);
        } else {
            for (int k = 0; k < B; k++) phaseA(k);
            for (int k = 0; k < B; k++) phaseB(k);
        }
    }

    if (deg == 0) { mn = 0.f; mx = 0.f; }
    float cf = (float)(deg > 0 ? deg : 1);
    float inv = 1.0f / cf;
    float mean = s * inv;
    float var = s2 * inv - mean * mean;
    float sd = sqrtf(fmaxf(var, 0.f) + 1e-5f);
    float ldv = logf(cf + 1.0f);
    float sc1 = ldv * (1.0f / AVG_LOG_F);
    float sc2 = AVG_LOG_F / ldv;

    // aggregators through LDS (rows 0..4), then post-MLP layer 1
    hb[w][0][l] = s;
    hb[w][1][l] = mean;
    hb[w][2][l] = mn;
    hb[w][3][l] = mx;
    hb[w][4][l] = sd;

    float p1 = qb1g;
#pragma unroll
    for (int f = 0; f < 16; f++) p1 = fmaf(xi[f], PW1[f * 16 + g], p1);
#pragma unroll
    for (int a = 0; a < 5; a++) {
        const float4* ap = (const float4*)&hb[w][a][t * 16];
        float4 a0 = ap[0], a1 = ap[1], a2 = ap[2], a3 = ap[3];
        float av[16] = {a0.x,a0.y,a0.z,a0.w, a1.x,a1.y,a1.z,a1.w,
                        a2.x,a2.y,a2.z,a2.w, a3.x,a3.y,a3.z,a3.w};
        int rb = 16 + a * 16;
#pragma unroll
        for (int f = 0; f < 16; f++) {
            float wv = fmaf(sc2, PW1[(rb + 160 + f) * 16 + g],
                       fmaf(sc1, PW1[(rb + 80 + f) * 16 + g],
                                 PW1[(rb + f) * 16 + g]));
            p1 = fmaf(av[f], wv, p1);
        }
    }
    p1 = fmaxf(p1, 0.f);

    // layer 2 through LDS row 5
    hb[w][5][l] = p1;
    {
        const float4* pp = (const float4*)&hb[w][5][t * 16];
        float4 p0 = pp[0], q1 = pp[1], q2 = pp[2], q3 = pp[3];
        float m2 = qb2g;
        m2 = fmaf(p0.x, pw2c[0],  m2); m2 = fmaf(p0.y, pw2c[1],  m2);
        m2 = fmaf(p0.z, pw2c[2],  m2); m2 = fmaf(p0.w, pw2c[3],  m2);
        m2 = fmaf(q1.x, pw2c[4],  m2); m2 = fmaf(q1.y, pw2c[5],  m2);
        m2 = fmaf(q1.z, pw2c[6],  m2); m2 = fmaf(q1.w, pw2c[7],  m2);
        m2 = fmaf(q2.x, pw2c[8],  m2); m2 = fmaf(q2.y, pw2c[9],  m2);
        m2 = fmaf(q2.z, pw2c[10], m2); m2 = fmaf(q2.w, pw2c[11], m2);
        m2 = fmaf(q3.x, pw2c[12], m2); m2 = fmaf(q3.y, pw2c[13], m2);
        m2 = fmaf(q3.z, pw2c[14], m2); m2 = fmaf(q3.w, pw2c[15], m2);
        p2f[(long)n * 64 + l] = m2;     // coalesced fp32 store
    }
}

// ---------------- 4: 64x64 linear + LayerNorm + ReLU + residual ----------------
__global__ __launch_bounds__(256) void k_final(
    const void* __restrict__ ax, const float* __restrict__ wsf,
    const float* __restrict__ p2f, void* __restrict__ outp, const int* __restrict__ modep,
    int* __restrict__ flags, int Nn)
{
    int tid = threadIdx.x;
    if (tid == 0 && blockIdx.x == 0) flags[1] = 1;
    int wid = (blockIdx.x * 256 + tid) >> 6;
    int l = tid & 63;
    int mode = modep[0];
    int n0 = wid * 4;
    if (n0 >= Nn) return;
    const float* LW = wsf + OFF_LW;
    float lb = wsf[OFF_LB + l];
    const float* r0 = p2f + (long)n0 * 64;
    float a0 = lb, a1 = lb, a2 = lb, a3 = lb;
#pragma unroll
    for (int f = 0; f < 64; f++) {
        float w = LW[f * 64 + l];
        a0 = fmaf(r0[f],       w, a0);
        a1 = fmaf(r0[64 + f],  w, a1);
        a2 = fmaf(r0[128 + f], w, a2);
        a3 = fmaf(r0[192 + f], w, a3);
    }
    float g = wsf[OFF_LG + l], be = wsf[OFF_LBN + l];
    float acc[4] = {a0, a1, a2, a3};
#pragma unroll
    for (int j = 0; j < 4; j++) {
        if (n0 + j >= Nn) break;
        float v = acc[j];
        float s1 = v, sq = v * v;
#pragma unroll
        for (int o = 1; o < 64; o <<= 1) { s1 += __shfl_xor(s1, o); sq += __shfl_xor(sq, o); }
        float mu = s1 * (1.0f / 64.0f);
        float var = sq * (1.0f / 64.0f) - mu * mu;
        float ln = (v - mu) * rsqrtf(var + 1e-5f) * g + be;
        long idx = (long)(n0 + j) * 64 + l;
        float res = rdin(ax, (int)idx, mode) + fmaxf(ln, 0.f);
        if (mode == 0) ((u16*)outp)[idx] = f2bf(res);
        else           ((float*)outp)[idx] = res;
    }
}

// ---------------- 5: diagnostic marker (no-op when healthy) ----------------
__global__ __launch_bounds__(64) void k_marker(
    const float* __restrict__ wsf, const float* __restrict__ p2f,
    void* __restrict__ outp, const int* __restrict__ modep,
    const int* __restrict__ flags, int Nn)
{
    if (threadIdx.x != 0 || blockIdx.x != 0) return;
    int code = 0;
    if (__float_as_uint(wsf[OFF_W1 + 5]) == 0xAAAAAAAAu) code |= 1;        // init dead
    if (__float_as_uint(p2f[0]) == 0xAAAAAAAAu &&
        __float_as_uint(p2f[1]) == 0xAAAAAAAAu) code |= 2;                 // p2 head unwritten
    long tl = (long)Nn * 64 - 2;
    if (__float_as_uint(p2f[tl]) == 0xAAAAAAAAu &&
        __float_as_uint(p2f[tl + 1]) == 0xAAAAAAAAu) code |= 4;            // p2 tail unwritten
    if (flags[0] == 0) code |= 8;                                          // k_node never entered
    if (flags[1] == 0) code |= 16;                                         // k_final never entered
    if (code != 0) {
        float val = 1024.0f * (float)code;
        if (modep[0] == 0) ((u16*)outp)[0] = f2bf(val);
        else               ((float*)outp)[0] = val;
    }
}

extern "C" void kernel_launch(void* const* d_in, const int* in_sizes, int n_in,
                              void* d_out, int out_size, void* d_ws, size_t ws_size,
                              hipStream_t stream) {
    const void* atom_x   = d_in[0];
    const void* bond_emb = d_in[1];
    const void* edge_w   = d_in[2];
    const void* edge_b   = d_in[3];
    const void* pre_w1   = d_in[4];
    const void* pre_b1   = d_in[5];
    const void* pre_w2   = d_in[6];
    const void* pre_b2   = d_in[7];
    const void* post_w1  = d_in[8];
    const void* post_b1  = d_in[9];
    const void* post_w2  = d_in[10];
    const void* post_b2  = d_in[11];
    const void* lin_w    = d_in[12];
    const void* lin_b    = d_in[13];
    const void* ln_g     = d_in[14];
    const void* ln_b     = d_in[15];
    const int* bond_x    = (const int*)d_in[16];
    const int* aei       = (const int*)d_in[17];

    int E  = in_sizes[16];
    int Nn = in_sizes[0] / 64;
    const int* srcp = aei;
    const int* dstp = aei + E;

    float* wsf = (float*)d_ws;
    int*   wsi = (int*)d_ws;

    size_t o = IB;
    int* modep = wsi + o; o += 16;
    int* flags = wsi + o; o += 48;
    int* cnt   = wsi + o; o += Nn;
    o = (o + 63) & ~(size_t)63;
    int* pk    = wsi + o; o += (size_t)Nn * MAXD;
    float* p2f = (float*)(wsi + o); o += (size_t)Nn * 64;
    // ws usage ~26 MB

    int NB = (Nn + 255) / 256;

    k_init<<<NB, 256, 0, stream>>>(bond_emb, edge_w, edge_b, pre_w1, pre_b1, pre_w2, pre_b2,
                                   post_w1, post_b1, post_w2, post_b2, lin_w, lin_b, ln_g, ln_b,
                                   atom_x, wsf, cnt, modep, flags, Nn);
    k_scatter<<<(E + 255) / 256, 256, 0, stream>>>(dstp, srcp, bond_x, cnt, pk, E);
    dim3 gn((Nn + 3) / 4, 1, 1);
    k_node<0><<<gn, 256, 0, stream>>>(atom_x, pk, cnt, wsf, p2f, modep, flags, Nn);
    k_node<1><<<gn, 256, 0, stream>>>(atom_x, pk, cnt, wsf, p2f, modep, flags, Nn);
    k_final<<<(Nn + 15) / 16, 256, 0, stream>>>(atom_x, wsf, p2f, d_out, modep, flags, Nn);
    k_marker<<<1, 64, 0, stream>>>(wsf, p2f, d_out, modep, flags, Nn);
}

// Round 8
// 381.786 us; speedup vs baseline: 2.8859x; 1.1962x over previous
//
#include <hip/hip_runtime.h>
#include <cstdint>

typedef unsigned short u16;

#define AVG_LOG_F 1.4862356961977451f
#define MAXD 64

// ---- workspace float-unit offsets (weights region) ----
#define OFF_W1   0      // pre_w1  fp32 [4][48][16]
#define OFF_W2   3072   // pre_w2  fp32 [4][16][16]
#define OFF_PW1  4096   // post_w1 fp32 [4][256][16]
#define OFF_PW2  20480  // post_w2 fp32 [4][16][16]
#define OFF_LW   21504  // lin_w   fp32 [64][64]
#define OFF_PB1  25600
#define OFF_PB2  25664
#define OFF_QB1  25728
#define OFF_QB2  25792
#define OFF_LB   25856
#define OFF_LG   25920
#define OFF_LBN  25984
#define OFF_ET   26048  // e_table fp32 [5][16]
#define IB       26176  // int region start (4B units)

__device__ __forceinline__ float bf2f(u16 u) {
    return __uint_as_float(((unsigned)u) << 16);
}
__device__ __forceinline__ u16 f2bf(float f) {
    unsigned u = __float_as_uint(f);
    u += 0x7fffu + ((u >> 16) & 1u);
    return (u16)(u >> 16);
}
__device__ __forceinline__ float rdin(const void* p, int j, int mode) {
    if (mode == 0) return bf2f(((const u16*)p)[j]);
    return ((const float*)p)[j];
}
template <int MODE>
__device__ __forceinline__ void load16c(const void* p, long base, float* o) {
    if (MODE == 0) {
        const u16* q = (const u16*)p + base;
        uint4 a = *(const uint4*)q;
        uint4 b = *(const uint4*)(q + 8);
        o[0]  = __uint_as_float(a.x << 16); o[1]  = __uint_as_float(a.x & 0xffff0000u);
        o[2]  = __uint_as_float(a.y << 16); o[3]  = __uint_as_float(a.y & 0xffff0000u);
        o[4]  = __uint_as_float(a.z << 16); o[5]  = __uint_as_float(a.z & 0xffff0000u);
        o[6]  = __uint_as_float(a.w << 16); o[7]  = __uint_as_float(a.w & 0xffff0000u);
        o[8]  = __uint_as_float(b.x << 16); o[9]  = __uint_as_float(b.x & 0xffff0000u);
        o[10] = __uint_as_float(b.y << 16); o[11] = __uint_as_float(b.y & 0xffff0000u);
        o[12] = __uint_as_float(b.z << 16); o[13] = __uint_as_float(b.z & 0xffff0000u);
        o[14] = __uint_as_float(b.w << 16); o[15] = __uint_as_float(b.w & 0xffff0000u);
    } else {
        const float* q = (const float*)p + base;
        float4 a = *(const float4*)q;
        float4 b = *(const float4*)(q + 4);
        float4 c = *(const float4*)(q + 8);
        float4 d = *(const float4*)(q + 12);
        o[0]=a.x; o[1]=a.y; o[2]=a.z; o[3]=a.w;
        o[4]=b.x; o[5]=b.y; o[6]=b.z; o[7]=b.w;
        o[8]=c.x; o[9]=c.y; o[10]=c.z; o[11]=c.w;
        o[12]=d.x; o[13]=d.y; o[14]=d.z; o[15]=d.w;
    }
}

// per-node Y precompute body: Y[n*64+l] = sum_f x[n][t*16+f] * pre_w1[t][(16+f)*16+g]
template <int MODE>
__device__ __forceinline__ void y_loop(const void* ax, const void* pre_w1, float* wsY,
                                       int Nn, int wave, int nwaves, int l) {
    const int t = l >> 4, g = l & 15;
    float w1c[16];
#pragma unroll
    for (int f = 0; f < 16; f++)
        w1c[f] = rdin(pre_w1, t * 768 + (16 + f) * 16 + g, MODE);
    for (int n = wave; n < Nn; n += nwaves) {
        float xj[16];
        load16c<MODE>(ax, (long)n * 64 + t * 16, xj);
        float acc = 0.f;
#pragma unroll
        for (int f = 0; f < 16; f++) acc = fmaf(xj[f], w1c[f], acc);
        wsY[(long)n * 64 + l] = acc;
    }
}

// ---------------- 1: init: detect dtype, zero cnt/flags, weights -> fp32, edge table, Y ----
__global__ __launch_bounds__(256) void k_init(
    const void* bond_emb, const void* edge_w, const void* edge_b,
    const void* pre_w1, const void* pre_b1, const void* pre_w2, const void* pre_b2,
    const void* post_w1, const void* post_b1, const void* post_w2, const void* post_b2,
    const void* lin_w, const void* lin_b, const void* ln_g, const void* ln_b,
    const void* ax, float* wsf, float* wsY, int* cnt, int* modep, int* flags, int Nn)
{
    __shared__ int csh;
    int tid = threadIdx.x;
    if (tid == 0) csh = 0;
    __syncthreads();
    {
        unsigned v = ((const unsigned*)ax)[tid];
        unsigned lo = v & 0xffffu;
        int e = (int)((lo >> 7) & 0xff);
        int isbf = (lo == 0u) || (e >= 110 && e <= 140);
        atomicAdd(&csh, isbf);
    }
    __syncthreads();
    int mode = (csh >= 192) ? 0 : 1;

    int gt = blockIdx.x * 256 + tid;
    int gs = gridDim.x * 256;
    if (gt < Nn) cnt[gt] = 0;
    if (blockIdx.x == 0 && tid == 0) { modep[0] = mode; flags[0] = 0; flags[1] = 0; }

    for (int j = gt; j < 3072; j += gs)  wsf[OFF_W1 + j]  = rdin(pre_w1, j, mode);
    for (int j = gt; j < 1024; j += gs)  wsf[OFF_W2 + j]  = rdin(pre_w2, j, mode);
    for (int j = gt; j < 16384; j += gs) wsf[OFF_PW1 + j] = rdin(post_w1, j, mode);
    for (int j = gt; j < 1024; j += gs)  wsf[OFF_PW2 + j] = rdin(post_w2, j, mode);
    for (int j = gt; j < 4096; j += gs)  wsf[OFF_LW + j]  = rdin(lin_w, j, mode);
    for (int j = gt; j < 64; j += gs) {
        wsf[OFF_PB1 + j] = rdin(pre_b1, j, mode);
        wsf[OFF_PB2 + j] = rdin(pre_b2, j, mode);
        wsf[OFF_QB1 + j] = rdin(post_b1, j, mode);
        wsf[OFF_QB2 + j] = rdin(post_b2, j, mode);
        wsf[OFF_LB + j]  = rdin(lin_b, j, mode);
        wsf[OFF_LG + j]  = rdin(ln_g, j, mode);
        wsf[OFF_LBN + j] = rdin(ln_b, j, mode);
    }
    if (gt < 80) {
        int b = gt >> 4, f = gt & 15;
        float acc = rdin(edge_b, f, mode);
        for (int k = 0; k < 64; k++)
            acc = fmaf(rdin(bond_emb, b * 64 + k, mode), rdin(edge_w, k * 16 + f, mode), acc);
        wsf[OFF_ET + gt] = acc;
    }
    // Y precompute: wave-per-node grid-stride (reads raw pre_w1, no dependence on wsf)
    int wave = gt >> 6;
    int nwaves = gs >> 6;
    int l = tid & 63;
    if (mode == 0) y_loop<0>(ax, pre_w1, wsY, Nn, wave, nwaves, l);
    else           y_loop<1>(ax, pre_w1, wsY, Nn, wave, nwaves, l);
}

// ---------------- 2: fused count+scatter into fixed-stride buckets ----------------
__global__ __launch_bounds__(256) void k_scatter(
    const int* __restrict__ dstp, const int* __restrict__ srcp, const int* __restrict__ bondp,
    int* __restrict__ cnt, int* __restrict__ pk, int E)
{
    int e = blockIdx.x * 256 + threadIdx.x;
    if (e < E) {
        int d = dstp[e];
        int pos = atomicAdd(&cnt[d], 1);
        if (pos < MAXD) pk[d * MAXD + pos] = (srcp[e] << 3) | (bondp[e] & 7);
    }
}

// ---------------- 3: wave-per-node fused kernel (64 lanes = 4 towers x 16 channels) --------
template <int MODE>
__global__ __launch_bounds__(256, 4) void k_node(
    const void* __restrict__ ax, const float* __restrict__ Yp,
    const int* __restrict__ pk, const int* __restrict__ cnt,
    const float* __restrict__ wsf, float* __restrict__ p2f,
    const int* __restrict__ modep, int* __restrict__ flags, int Nn)
{
    if (modep[0] != MODE) return;
    if (threadIdx.x == 0 && blockIdx.x == 0) flags[0] = 1;
    __shared__ float hb[4][16][64];
    const int w = threadIdx.x >> 6;
    const int l = threadIdx.x & 63;
    const int t = l >> 4;
    const int g = l & 15;
    const int n = blockIdx.x * 4 + w;
    if (n >= Nn) return;

    const float* W1  = wsf + OFF_W1  + t * 768;
    const float* W2  = wsf + OFF_W2  + t * 256;
    const float* PW1 = wsf + OFF_PW1 + t * 4096;
    const float* PW2 = wsf + OFF_PW2 + t * 256;
    const float* ET  = wsf + OFF_ET;

    float w2c[16], pw2c[16];
#pragma unroll
    for (int f = 0; f < 16; f++) {
        w2c[f]  = W2[f * 16 + g];
        pw2c[f] = PW2[f * 16 + g];
    }
    float pb1g = wsf[OFF_PB1 + t * 16 + g];
    float pb2g = wsf[OFF_PB2 + t * 16 + g];
    float qb1g = wsf[OFF_QB1 + t * 16 + g];
    float qb2g = wsf[OFF_QB2 + t * 16 + g];

    int deg = cnt[n];
    if (deg > MAXD) deg = MAXD;
    const int* pkrow = pk + n * MAXD;

    float xi[16];
    load16c<MODE>(ax, (long)n * 64 + t * 16, xi);
    float xiW = 0.f;
#pragma unroll
    for (int f = 0; f < 16; f++) xiW = fmaf(xi[f], W1[f * 16 + g], xiW);

    // zw[b] = xiW + pre_b1 + (edge-table b) . W1_e  — everything per-edge-invariant
    float zw0, zw1, zw2, zw3, zw4;
    {
        float a0 = pb1g, a1 = pb1g, a2 = pb1g, a3 = pb1g, a4 = pb1g;
#pragma unroll
        for (int f = 0; f < 16; f++) {
            float wc = W1[(32 + f) * 16 + g];
            a0 = fmaf(ET[0 * 16 + f], wc, a0);
            a1 = fmaf(ET[1 * 16 + f], wc, a1);
            a2 = fmaf(ET[2 * 16 + f], wc, a2);
            a3 = fmaf(ET[3 * 16 + f], wc, a3);
            a4 = fmaf(ET[4 * 16 + f], wc, a4);
        }
        zw0 = a0 + xiW; zw1 = a1 + xiW; zw2 = a2 + xiW; zw3 = a3 + xiW; zw4 = a4 + xiW;
    }

    float s = 0.f, s2 = 0.f, mn = 3.0e38f, mx = -3.0e38f;

    for (int kb = 0; kb < deg; kb += 16) {
        int B = deg - kb; if (B > 16) B = 16;
        int pkv = (l < B) ? pkrow[kb + l] : 0;

        auto phaseA = [&](int k) {
            int v = __builtin_amdgcn_readfirstlane(__shfl(pkv, k, 64));
            float yv = Yp[((long)(v >> 3) << 6) + l];     // 1 coalesced 256B gather
            int bd = v & 7;
            float h = yv + ((bd == 0) ? zw0 : (bd == 1) ? zw1 : (bd == 2) ? zw2
                             : (bd == 3) ? zw3 : zw4);
            hb[w][k][l] = fmaxf(h, 0.f);
        };
        auto phaseB = [&](int k) {
            const float4* hp = (const float4*)&hb[w][k][t * 16];
            float4 h0 = hp[0], h1 = hp[1], h2 = hp[2], h3 = hp[3];
            float m = pb2g;
            m = fmaf(h0.x, w2c[0],  m); m = fmaf(h0.y, w2c[1],  m);
            m = fmaf(h0.z, w2c[2],  m); m = fmaf(h0.w, w2c[3],  m);
            m = fmaf(h1.x, w2c[4],  m); m = fmaf(h1.y, w2c[5],  m);
            m = fmaf(h1.z, w2c[6],  m); m = fmaf(h1.w, w2c[7],  m);
            m = fmaf(h2.x, w2c[8],  m); m = fmaf(h2.y, w2c[9],  m);
            m = fmaf(h2.z, w2c[10], m); m = fmaf(h2.w, w2c[11], m);
            m = fmaf(h3.x, w2c[12], m); m = fmaf(h3.y, w2c[13], m);
            m = fmaf(h3.z, w2c[14], m); m = fmaf(h3.w, w2c[15], m);
            s += m;
            s2 = fmaf(m, m, s2);
            mn = fminf(mn, m);
            mx = fmaxf(mx, m);
        };
        if (B == 16) {
#pragma unroll 8
            for (int k = 0; k < 16; k++) phaseA(k);
#pragma unroll 4
            for (int k = 0; k < 16; k++) phaseB(k);
        } else {
            for (int k = 0; k < B; k++) phaseA(k);
            for (int k = 0; k < B; k++) phaseB(k);
        }
    }

    if (deg == 0) { mn = 0.f; mx = 0.f; }
    float cf = (float)(deg > 0 ? deg : 1);
    float inv = 1.0f / cf;
    float mean = s * inv;
    float var = s2 * inv - mean * mean;
    float sd = sqrtf(fmaxf(var, 0.f) + 1e-5f);
    float ldv = logf(cf + 1.0f);
    float sc1 = ldv * (1.0f / AVG_LOG_F);
    float sc2 = AVG_LOG_F / ldv;

    hb[w][0][l] = s;
    hb[w][1][l] = mean;
    hb[w][2][l] = mn;
    hb[w][3][l] = mx;
    hb[w][4][l] = sd;

    float p1 = qb1g;
#pragma unroll
    for (int f = 0; f < 16; f++) p1 = fmaf(xi[f], PW1[f * 16 + g], p1);
#pragma unroll
    for (int a = 0; a < 5; a++) {
        const float4* ap = (const float4*)&hb[w][a][t * 16];
        float4 a0 = ap[0], a1 = ap[1], a2 = ap[2], a3 = ap[3];
        float av[16] = {a0.x,a0.y,a0.z,a0.w, a1.x,a1.y,a1.z,a1.w,
                        a2.x,a2.y,a2.z,a2.w, a3.x,a3.y,a3.z,a3.w};
        int rb = 16 + a * 16;
#pragma unroll
        for (int f = 0; f < 16; f++) {
            float wv = fmaf(sc2, PW1[(rb + 160 + f) * 16 + g],
                       fmaf(sc1, PW1[(rb + 80 + f) * 16 + g],
                                 PW1[(rb + f) * 16 + g]));
            p1 = fmaf(av[f], wv, p1);
        }
    }
    p1 = fmaxf(p1, 0.f);

    hb[w][5][l] = p1;
    {
        const float4* pp = (const float4*)&hb[w][5][t * 16];
        float4 p0 = pp[0], q1 = pp[1], q2 = pp[2], q3 = pp[3];
        float m2 = qb2g;
        m2 = fmaf(p0.x, pw2c[0],  m2); m2 = fmaf(p0.y, pw2c[1],  m2);
        m2 = fmaf(p0.z, pw2c[2],  m2); m2 = fmaf(p0.w, pw2c[3],  m2);
        m2 = fmaf(q1.x, pw2c[4],  m2); m2 = fmaf(q1.y, pw2c[5],  m2);
        m2 = fmaf(q1.z, pw2c[6],  m2); m2 = fmaf(q1.w, pw2c[7],  m2);
        m2 = fmaf(q2.x, pw2c[8],  m2); m2 = fmaf(q2.y, pw2c[9],  m2);
        m2 = fmaf(q2.z, pw2c[10], m2); m2 = fmaf(q2.w, pw2c[11], m2);
        m2 = fmaf(q3.x, pw2c[12], m2); m2 = fmaf(q3.y, pw2c[13], m2);
        m2 = fmaf(q3.z, pw2c[14], m2); m2 = fmaf(q3.w, pw2c[15], m2);
        p2f[(long)n * 64 + l] = m2;
    }
}

// ---------------- 4: 64x64 linear + LayerNorm + ReLU + residual ----------------
__global__ __launch_bounds__(256) void k_final(
    const void* __restrict__ ax, const float* __restrict__ wsf,
    const float* __restrict__ p2f, void* __restrict__ outp, const int* __restrict__ modep,
    int* __restrict__ flags, int Nn)
{
    int tid = threadIdx.x;
    if (tid == 0 && blockIdx.x == 0) flags[1] = 1;
    int wid = __builtin_amdgcn_readfirstlane((blockIdx.x * 256 + tid) >> 6);
    int l = tid & 63;
    int mode = modep[0];
    int n0 = wid * 4;
    if (n0 >= Nn) return;
    const float* LW = wsf + OFF_LW;
    float lb = wsf[OFF_LB + l];
    const float* r0 = p2f + (long)n0 * 64;       // scalar base -> s_load batches
    float a0 = lb, a1 = lb, a2 = lb, a3 = lb;
#pragma unroll
    for (int f = 0; f < 64; f++) {
        float w = LW[f * 64 + l];
        a0 = fmaf(r0[f],       w, a0);
        a1 = fmaf(r0[64 + f],  w, a1);
        a2 = fmaf(r0[128 + f], w, a2);
        a3 = fmaf(r0[192 + f], w, a3);
    }
    float g = wsf[OFF_LG + l], be = wsf[OFF_LBN + l];
    float acc[4] = {a0, a1, a2, a3};
#pragma unroll
    for (int j = 0; j < 4; j++) {
        if (n0 + j >= Nn) break;
        float v = acc[j];
        float s1 = v, sq = v * v;
#pragma unroll
        for (int o = 1; o < 64; o <<= 1) { s1 += __shfl_xor(s1, o); sq += __shfl_xor(sq, o); }
        float mu = s1 * (1.0f / 64.0f);
        float var = sq * (1.0f / 64.0f) - mu * mu;
        float ln = (v - mu) * rsqrtf(var + 1e-5f) * g + be;
        long idx = (long)(n0 + j) * 64 + l;
        float res = rdin(ax, (int)idx, mode) + fmaxf(ln, 0.f);
        if (mode == 0) ((u16*)outp)[idx] = f2bf(res);
        else           ((float*)outp)[idx] = res;
    }
}

// ---------------- 5: diagnostic marker (no-op when healthy) ----------------
__global__ __launch_bounds__(64) void k_marker(
    const float* __restrict__ wsf, const float* __restrict__ p2f, const float* __restrict__ Yp,
    void* __restrict__ outp, const int* __restrict__ modep,
    const int* __restrict__ flags, int Nn)
{
    if (threadIdx.x != 0 || blockIdx.x != 0) return;
    int code = 0;
    if (__float_as_uint(wsf[OFF_W1 + 5]) == 0xAAAAAAAAu) code |= 1;        // init dead
    if (__float_as_uint(Yp[0]) == 0xAAAAAAAAu &&
        __float_as_uint(Yp[1]) == 0xAAAAAAAAu) code |= 2;                  // Y unwritten
    if (__float_as_uint(p2f[0]) == 0xAAAAAAAAu &&
        __float_as_uint(p2f[1]) == 0xAAAAAAAAu) code |= 4;                 // p2 head unwritten
    long tl = (long)Nn * 64 - 2;
    if (__float_as_uint(p2f[tl]) == 0xAAAAAAAAu &&
        __float_as_uint(p2f[tl + 1]) == 0xAAAAAAAAu) code |= 8;            // p2 tail unwritten
    if (flags[0] == 0) code |= 16;                                         // k_node never entered
    if (flags[1] == 0) code |= 32;                                         // k_final never entered
    if (code != 0) {
        float val = 1024.0f * (float)code;
        if (modep[0] == 0) ((u16*)outp)[0] = f2bf(val);
        else               ((float*)outp)[0] = val;
    }
}

extern "C" void kernel_launch(void* const* d_in, const int* in_sizes, int n_in,
                              void* d_out, int out_size, void* d_ws, size_t ws_size,
                              hipStream_t stream) {
    const void* atom_x   = d_in[0];
    const void* bond_emb = d_in[1];
    const void* edge_w   = d_in[2];
    const void* edge_b   = d_in[3];
    const void* pre_w1   = d_in[4];
    const void* pre_b1   = d_in[5];
    const void* pre_w2   = d_in[6];
    const void* pre_b2   = d_in[7];
    const void* post_w1  = d_in[8];
    const void* post_b1  = d_in[9];
    const void* post_w2  = d_in[10];
    const void* post_b2  = d_in[11];
    const void* lin_w    = d_in[12];
    const void* lin_b    = d_in[13];
    const void* ln_g     = d_in[14];
    const void* ln_b     = d_in[15];
    const int* bond_x    = (const int*)d_in[16];
    const int* aei       = (const int*)d_in[17];

    int E  = in_sizes[16];
    int Nn = in_sizes[0] / 64;
    const int* srcp = aei;
    const int* dstp = aei + E;

    float* wsf = (float*)d_ws;
    int*   wsi = (int*)d_ws;

    size_t o = IB;
    int* modep = wsi + o; o += 16;
    int* flags = wsi + o; o += 48;
    int* cnt   = wsi + o; o += Nn;
    o = (o + 63) & ~(size_t)63;
    int* pk    = wsi + o; o += (size_t)Nn * MAXD;
    float* Yp  = (float*)(wsi + o); o += (size_t)Nn * 64;
    float* p2f = (float*)(wsi + o); o += (size_t)Nn * 64;
    // ws usage ~39 MB

    int NB = (Nn + 255) / 256;

    k_init<<<NB, 256, 0, stream>>>(bond_emb, edge_w, edge_b, pre_w1, pre_b1, pre_w2, pre_b2,
                                   post_w1, post_b1, post_w2, post_b2, lin_w, lin_b, ln_g, ln_b,
                                   atom_x, wsf, Yp, cnt, modep, flags, Nn);
    k_scatter<<<(E + 255) / 256, 256, 0, stream>>>(dstp, srcp, bond_x, cnt, pk, E);
    dim3 gn((Nn + 3) / 4, 1, 1);
    k_node<0><<<gn, 256, 0, stream>>>(atom_x, Yp, pk, cnt, wsf, p2f, modep, flags, Nn);
    k_node<1><<<gn, 256, 0, stream>>>(atom_x, Yp, pk, cnt, wsf, p2f, modep, flags, Nn);
    k_final<<<(Nn + 15) / 16, 256, 0, stream>>>(atom_x, wsf, p2f, d_out, modep, flags, Nn);
    k_marker<<<1, 64, 0, stream>>>(wsf, p2f, Yp, d_out, modep, flags, Nn);
}

// Round 9
// 365.779 us; speedup vs baseline: 3.0122x; 1.0438x over previous
//
#include <hip/hip_runtime.h>
#include <cstdint>

typedef unsigned short u16;

#define AVG_LOG_F 1.4862356961977451f
#define MAXD 64

// ---- workspace float-unit offsets (weights region) ----
#define OFF_W1   0      // pre_w1  fp32 [4][48][16]
#define OFF_W2   3072   // pre_w2  fp32 [4][16][16]
#define OFF_PW1  4096   // post_w1 fp32 [4][256][16]
#define OFF_PW2  20480  // post_w2 fp32 [4][16][16]
#define OFF_LW   21504  // lin_w   fp32 [64][64]
#define OFF_PB1  25600
#define OFF_PB2  25664
#define OFF_QB1  25728
#define OFF_QB2  25792
#define OFF_LB   25856
#define OFF_LG   25920
#define OFF_LBN  25984
#define OFF_ET   26048  // e_table fp32 [5][16]
#define OFF_EWT  26128  // eWtab  fp32 [5][64]  (pb1 + ET.W1e, node-invariant)
#define IB       26448  // int region start (4B units)

__device__ __forceinline__ float bf2f(u16 u) {
    return __uint_as_float(((unsigned)u) << 16);
}
__device__ __forceinline__ u16 f2bf(float f) {
    unsigned u = __float_as_uint(f);
    u += 0x7fffu + ((u >> 16) & 1u);
    return (u16)(u >> 16);
}
__device__ __forceinline__ float rdin(const void* p, int j, int mode) {
    if (mode == 0) return bf2f(((const u16*)p)[j]);
    return ((const float*)p)[j];
}
template <int MODE>
__device__ __forceinline__ void load16c(const void* p, long base, float* o) {
    if (MODE == 0) {
        const u16* q = (const u16*)p + base;
        uint4 a = *(const uint4*)q;
        uint4 b = *(const uint4*)(q + 8);
        o[0]  = __uint_as_float(a.x << 16); o[1]  = __uint_as_float(a.x & 0xffff0000u);
        o[2]  = __uint_as_float(a.y << 16); o[3]  = __uint_as_float(a.y & 0xffff0000u);
        o[4]  = __uint_as_float(a.z << 16); o[5]  = __uint_as_float(a.z & 0xffff0000u);
        o[6]  = __uint_as_float(a.w << 16); o[7]  = __uint_as_float(a.w & 0xffff0000u);
        o[8]  = __uint_as_float(b.x << 16); o[9]  = __uint_as_float(b.x & 0xffff0000u);
        o[10] = __uint_as_float(b.y << 16); o[11] = __uint_as_float(b.y & 0xffff0000u);
        o[12] = __uint_as_float(b.z << 16); o[13] = __uint_as_float(b.z & 0xffff0000u);
        o[14] = __uint_as_float(b.w << 16); o[15] = __uint_as_float(b.w & 0xffff0000u);
    } else {
        const float* q = (const float*)p + base;
        float4 a = *(const float4*)q;
        float4 b = *(const float4*)(q + 4);
        float4 c = *(const float4*)(q + 8);
        float4 d = *(const float4*)(q + 12);
        o[0]=a.x; o[1]=a.y; o[2]=a.z; o[3]=a.w;
        o[4]=b.x; o[5]=b.y; o[6]=b.z; o[7]=b.w;
        o[8]=c.x; o[9]=c.y; o[10]=c.z; o[11]=c.w;
        o[12]=d.x; o[13]=d.y; o[14]=d.z; o[15]=d.w;
    }
}

// per-node precompute: Y[n][l] = x[n].W1_xj column,  XW[n][l] = x[n].W1_xi column
template <int MODE>
__device__ __forceinline__ void y_loop(const void* ax, const void* pre_w1, float* wsY, float* wsXW,
                                       int Nn, int wave, int nwaves, int l) {
    const int t = l >> 4, g = l & 15;
    float wxi[16], wxj[16];
#pragma unroll
    for (int f = 0; f < 16; f++) {
        wxi[f] = rdin(pre_w1, t * 768 + f * 16 + g, MODE);
        wxj[f] = rdin(pre_w1, t * 768 + (16 + f) * 16 + g, MODE);
    }
    for (int n = wave; n < Nn; n += nwaves) {
        float xj[16];
        load16c<MODE>(ax, (long)n * 64 + t * 16, xj);
        float accY = 0.f, accX = 0.f;
#pragma unroll
        for (int f = 0; f < 16; f++) {
            accY = fmaf(xj[f], wxj[f], accY);
            accX = fmaf(xj[f], wxi[f], accX);
        }
        wsY[(long)n * 64 + l]  = accY;
        wsXW[(long)n * 64 + l] = accX;
    }
}

// ---------------- 1: init: dtype, zero cnt, weights -> fp32, ET, Y, XW ----------------
__global__ __launch_bounds__(256) void k_init(
    const void* bond_emb, const void* edge_w, const void* edge_b,
    const void* pre_w1, const void* pre_b1, const void* pre_w2, const void* pre_b2,
    const void* post_w1, const void* post_b1, const void* post_w2, const void* post_b2,
    const void* lin_w, const void* lin_b, const void* ln_g, const void* ln_b,
    const void* ax, float* wsf, float* wsY, float* wsXW, int* cnt, int* modep, int Nn)
{
    __shared__ int csh;
    int tid = threadIdx.x;
    if (tid == 0) csh = 0;
    __syncthreads();
    {
        unsigned v = ((const unsigned*)ax)[tid];
        unsigned lo = v & 0xffffu;
        int e = (int)((lo >> 7) & 0xff);
        int isbf = (lo == 0u) || (e >= 110 && e <= 140);
        atomicAdd(&csh, isbf);
    }
    __syncthreads();
    int mode = (csh >= 192) ? 0 : 1;

    int gt = blockIdx.x * 256 + tid;
    int gs = gridDim.x * 256;
    if (gt < Nn) cnt[gt] = 0;
    if (blockIdx.x == 0 && tid == 0) modep[0] = mode;

    for (int j = gt; j < 3072; j += gs)  wsf[OFF_W1 + j]  = rdin(pre_w1, j, mode);
    for (int j = gt; j < 1024; j += gs)  wsf[OFF_W2 + j]  = rdin(pre_w2, j, mode);
    for (int j = gt; j < 16384; j += gs) wsf[OFF_PW1 + j] = rdin(post_w1, j, mode);
    for (int j = gt; j < 1024; j += gs)  wsf[OFF_PW2 + j] = rdin(post_w2, j, mode);
    for (int j = gt; j < 4096; j += gs)  wsf[OFF_LW + j]  = rdin(lin_w, j, mode);
    for (int j = gt; j < 64; j += gs) {
        wsf[OFF_PB1 + j] = rdin(pre_b1, j, mode);
        wsf[OFF_PB2 + j] = rdin(pre_b2, j, mode);
        wsf[OFF_QB1 + j] = rdin(post_b1, j, mode);
        wsf[OFF_QB2 + j] = rdin(post_b2, j, mode);
        wsf[OFF_LB + j]  = rdin(lin_b, j, mode);
        wsf[OFF_LG + j]  = rdin(ln_g, j, mode);
        wsf[OFF_LBN + j] = rdin(ln_b, j, mode);
    }
    if (gt < 80) {
        int b = gt >> 4, f = gt & 15;
        float acc = rdin(edge_b, f, mode);
        for (int k = 0; k < 64; k++)
            acc = fmaf(rdin(bond_emb, b * 64 + k, mode), rdin(edge_w, k * 16 + f, mode), acc);
        wsf[OFF_ET + gt] = acc;
    }
    int wave = gt >> 6;
    int nwaves = gs >> 6;
    int l = tid & 63;
    if (mode == 0) y_loop<0>(ax, pre_w1, wsY, wsXW, Nn, wave, nwaves, l);
    else           y_loop<1>(ax, pre_w1, wsY, wsXW, Nn, wave, nwaves, l);
}

// ---------------- 2: count+scatter into fixed-stride buckets; block 0 also builds eWtab ----
__global__ __launch_bounds__(256) void k_scatter(
    const int* __restrict__ dstp, const int* __restrict__ srcp, const int* __restrict__ bondp,
    int* __restrict__ cnt, int* __restrict__ pk, float* __restrict__ wsf, int E)
{
    if (blockIdx.x == 0) {
        for (int j = threadIdx.x; j < 320; j += 256) {
            int b = j >> 6, ll = j & 63, tt = ll >> 4, gg = ll & 15;
            float acc = wsf[OFF_PB1 + tt * 16 + gg];
#pragma unroll
            for (int f = 0; f < 16; f++)
                acc = fmaf(wsf[OFF_ET + b * 16 + f], wsf[OFF_W1 + tt * 768 + (32 + f) * 16 + gg], acc);
            wsf[OFF_EWT + j] = acc;
        }
    }
    int e = blockIdx.x * 256 + threadIdx.x;
    if (e < E) {
        int d = dstp[e];
        int pos = atomicAdd(&cnt[d], 1);
        if (pos < MAXD) pk[d * MAXD + pos] = (srcp[e] << 3) | (bondp[e] & 7);
    }
}

// ---------------- 3: wave-per-node fused kernel (64 lanes = 4 towers x 16 channels) --------
__global__ __launch_bounds__(256, 4) void k_node(
    const void* __restrict__ ax, const float* __restrict__ Yp, const float* __restrict__ XWp,
    const int* __restrict__ pk, const int* __restrict__ cnt,
    const float* __restrict__ wsf, float* __restrict__ p2f,
    const int* __restrict__ modep, int Nn)
{
    __shared__ float hb[4][16][64];
    const int w = threadIdx.x >> 6;
    const int l = threadIdx.x & 63;
    const int t = l >> 4;
    const int g = l & 15;
    const int n = blockIdx.x * 4 + w;
    if (n >= Nn) return;
    const int mode = modep[0];

    const float* W2  = wsf + OFF_W2  + t * 256;
    const float* PW1 = wsf + OFF_PW1 + t * 4096;
    const float* PW2 = wsf + OFF_PW2 + t * 256;

    float w2c[16], pw2c[16];
#pragma unroll
    for (int f = 0; f < 16; f++) {
        w2c[f]  = W2[f * 16 + g];
        pw2c[f] = PW2[f * 16 + g];
    }
    float pb2g = wsf[OFF_PB2 + t * 16 + g];
    float qb1g = wsf[OFF_QB1 + t * 16 + g];
    float qb2g = wsf[OFF_QB2 + t * 16 + g];

    int deg = cnt[n];
    if (deg > MAXD) deg = MAXD;

    int   pkvAll = pk[n * MAXD + l];            // whole bucket row, one load
    float XWv    = XWp[(long)n * 64 + l];
    float zw0 = XWv + wsf[OFF_EWT + 0 * 64 + l];
    float zw1 = XWv + wsf[OFF_EWT + 1 * 64 + l];
    float zw2 = XWv + wsf[OFF_EWT + 2 * 64 + l];
    float zw3 = XWv + wsf[OFF_EWT + 3 * 64 + l];
    float zw4 = XWv + wsf[OFF_EWT + 4 * 64 + l];

    float xi[16];
    if (mode == 0) load16c<0>(ax, (long)n * 64 + t * 16, xi);
    else           load16c<1>(ax, (long)n * 64 + t * 16, xi);

    float s = 0.f, s2 = 0.f, mn = 3.0e38f, mx = -3.0e38f;

    auto phaseA = [&](int srclane, int k) {
        int v = __builtin_amdgcn_readlane(pkvAll, srclane);
        const float* yrow = Yp + ((long)(v >> 3) << 6);
        float yv = yrow[l];
        int bd = v & 7;
        float h = yv + ((bd == 0) ? zw0 : (bd == 1) ? zw1 : (bd == 2) ? zw2
                         : (bd == 3) ? zw3 : zw4);
        hb[w][k][l] = fmaxf(h, 0.f);
    };
    auto phaseB = [&](int k) {
        const float4* hp = (const float4*)&hb[w][k][t * 16];
        float4 h0 = hp[0], h1 = hp[1], h2 = hp[2], h3 = hp[3];
        float m = pb2g;
        m = fmaf(h0.x, w2c[0],  m); m = fmaf(h0.y, w2c[1],  m);
        m = fmaf(h0.z, w2c[2],  m); m = fmaf(h0.w, w2c[3],  m);
        m = fmaf(h1.x, w2c[4],  m); m = fmaf(h1.y, w2c[5],  m);
        m = fmaf(h1.z, w2c[6],  m); m = fmaf(h1.w, w2c[7],  m);
        m = fmaf(h2.x, w2c[8],  m); m = fmaf(h2.y, w2c[9],  m);
        m = fmaf(h2.z, w2c[10], m); m = fmaf(h2.w, w2c[11], m);
        m = fmaf(h3.x, w2c[12], m); m = fmaf(h3.y, w2c[13], m);
        m = fmaf(h3.z, w2c[14], m); m = fmaf(h3.w, w2c[15], m);
        s += m;
        s2 = fmaf(m, m, s2);
        mn = fminf(mn, m);
        mx = fmaxf(mx, m);
    };

#pragma unroll
    for (int kb = 0; kb < MAXD; kb += 16) {
        if (kb >= deg) break;
        int B = deg - kb; if (B > 16) B = 16;
        if (B == 16) {
#pragma unroll
            for (int k = 0; k < 16; k++) phaseA(kb + k, k);   // literal lanes -> v_readlane
#pragma unroll 4
            for (int k = 0; k < 16; k++) phaseB(k);
        } else {
            for (int k = 0; k < B; k++) phaseA(kb + k, k);    // uniform dynamic lane
            for (int k = 0; k < B; k++) phaseB(k);
        }
    }

    if (deg == 0) { mn = 0.f; mx = 0.f; }
    float cf = (float)(deg > 0 ? deg : 1);
    float inv = 1.0f / cf;
    float mean = s * inv;
    float var = s2 * inv - mean * mean;
    float sd = sqrtf(fmaxf(var, 0.f) + 1e-5f);
    float ldv = logf(cf + 1.0f);
    float sc1 = ldv * (1.0f / AVG_LOG_F);
    float sc2 = AVG_LOG_F / ldv;

    hb[w][0][l] = s;
    hb[w][1][l] = mean;
    hb[w][2][l] = mn;
    hb[w][3][l] = mx;
    hb[w][4][l] = sd;

    float p1 = qb1g;
#pragma unroll
    for (int f = 0; f < 16; f++) p1 = fmaf(xi[f], PW1[f * 16 + g], p1);
#pragma unroll
    for (int a = 0; a < 5; a++) {
        const float4* ap = (const float4*)&hb[w][a][t * 16];
        float4 a0 = ap[0], a1 = ap[1], a2 = ap[2], a3 = ap[3];
        float av[16] = {a0.x,a0.y,a0.z,a0.w, a1.x,a1.y,a1.z,a1.w,
                        a2.x,a2.y,a2.z,a2.w, a3.x,a3.y,a3.z,a3.w};
        int rb = 16 + a * 16;
#pragma unroll
        for (int f = 0; f < 16; f++) {
            float wv = fmaf(sc2, PW1[(rb + 160 + f) * 16 + g],
                       fmaf(sc1, PW1[(rb + 80 + f) * 16 + g],
                                 PW1[(rb + f) * 16 + g]));
            p1 = fmaf(av[f], wv, p1);
        }
    }
    p1 = fmaxf(p1, 0.f);

    hb[w][5][l] = p1;
    {
        const float4* pp = (const float4*)&hb[w][5][t * 16];
        float4 p0 = pp[0], q1 = pp[1], q2 = pp[2], q3 = pp[3];
        float m2 = qb2g;
        m2 = fmaf(p0.x, pw2c[0],  m2); m2 = fmaf(p0.y, pw2c[1],  m2);
        m2 = fmaf(p0.z, pw2c[2],  m2); m2 = fmaf(p0.w, pw2c[3],  m2);
        m2 = fmaf(q1.x, pw2c[4],  m2); m2 = fmaf(q1.y, pw2c[5],  m2);
        m2 = fmaf(q1.z, pw2c[6],  m2); m2 = fmaf(q1.w, pw2c[7],  m2);
        m2 = fmaf(q2.x, pw2c[8],  m2); m2 = fmaf(q2.y, pw2c[9],  m2);
        m2 = fmaf(q2.z, pw2c[10], m2); m2 = fmaf(q2.w, pw2c[11], m2);
        m2 = fmaf(q3.x, pw2c[12], m2); m2 = fmaf(q3.y, pw2c[13], m2);
        m2 = fmaf(q3.z, pw2c[14], m2); m2 = fmaf(q3.w, pw2c[15], m2);
        p2f[(long)n * 64 + l] = m2;
    }
}

// ---------------- 4: 64x64 linear + LayerNorm + ReLU + residual (+ marker) ----------------
__global__ __launch_bounds__(256) void k_final(
    const void* __restrict__ ax, const float* __restrict__ wsf,
    const float* __restrict__ p2f, const float* __restrict__ Yp, const float* __restrict__ XWp,
    void* __restrict__ outp, const int* __restrict__ modep, int Nn)
{
    int tid = threadIdx.x;
    int mode = modep[0];
    // diagnostic marker: only writes on structural failure
    if (blockIdx.x == gridDim.x - 1 && tid == 255) {
        int code = 0;
        if (__float_as_uint(wsf[OFF_W1 + 5]) == 0xAAAAAAAAu) code |= 1;
        if (__float_as_uint(Yp[0]) == 0xAAAAAAAAu && __float_as_uint(Yp[1]) == 0xAAAAAAAAu) code |= 2;
        if (__float_as_uint(XWp[0]) == 0xAAAAAAAAu && __float_as_uint(XWp[1]) == 0xAAAAAAAAu) code |= 4;
        if (__float_as_uint(p2f[0]) == 0xAAAAAAAAu && __float_as_uint(p2f[1]) == 0xAAAAAAAAu) code |= 8;
        long tl = (long)Nn * 64 - 2;
        if (__float_as_uint(p2f[tl]) == 0xAAAAAAAAu && __float_as_uint(p2f[tl + 1]) == 0xAAAAAAAAu) code |= 16;
        if (code != 0) {
            float val = 1024.0f * (float)code;
            if (mode == 0) ((u16*)outp)[1] = f2bf(val);
            else           ((float*)outp)[1] = val;
        }
    }
    int wid = __builtin_amdgcn_readfirstlane((blockIdx.x * 256 + tid) >> 6);
    int l = tid & 63;
    int n0 = wid * 4;
    if (n0 >= Nn) return;
    const float* LW = wsf + OFF_LW;
    float lb = wsf[OFF_LB + l];
    const float* r0 = p2f + (long)n0 * 64;
    float a0 = lb, a1 = lb, a2 = lb, a3 = lb;
#pragma unroll
    for (int f = 0; f < 64; f++) {
        float w = LW[f * 64 + l];
        a0 = fmaf(r0[f],       w, a0);
        a1 = fmaf(r0[64 + f],  w, a1);
        a2 = fmaf(r0[128 + f], w, a2);
        a3 = fmaf(r0[192 + f], w, a3);
    }
    float g = wsf[OFF_LG + l], be = wsf[OFF_LBN + l];
    float acc[4] = {a0, a1, a2, a3};
#pragma unroll
    for (int j = 0; j < 4; j++) {
        if (n0 + j >= Nn) break;
        float v = acc[j];
        float s1 = v, sq = v * v;
#pragma unroll
        for (int o = 1; o < 64; o <<= 1) { s1 += __shfl_xor(s1, o); sq += __shfl_xor(sq, o); }
        float mu = s1 * (1.0f / 64.0f);
        float var = sq * (1.0f / 64.0f) - mu * mu;
        float ln = (v - mu) * rsqrtf(var + 1e-5f) * g + be;
        long idx = (long)(n0 + j) * 64 + l;
        float res = rdin(ax, (int)idx, mode) + fmaxf(ln, 0.f);
        if (mode == 0) ((u16*)outp)[idx] = f2bf(res);
        else           ((float*)outp)[idx] = res;
    }
}

extern "C" void kernel_launch(void* const* d_in, const int* in_sizes, int n_in,
                              void* d_out, int out_size, void* d_ws, size_t ws_size,
                              hipStream_t stream) {
    const void* atom_x   = d_in[0];
    const void* bond_emb = d_in[1];
    const void* edge_w   = d_in[2];
    const void* edge_b   = d_in[3];
    const void* pre_w1   = d_in[4];
    const void* pre_b1   = d_in[5];
    const void* pre_w2   = d_in[6];
    const void* pre_b2   = d_in[7];
    const void* post_w1  = d_in[8];
    const void* post_b1  = d_in[9];
    const void* post_w2  = d_in[10];
    const void* post_b2  = d_in[11];
    const void* lin_w    = d_in[12];
    const void* lin_b    = d_in[13];
    const void* ln_g     = d_in[14];
    const void* ln_b     = d_in[15];
    const int* bond_x    = (const int*)d_in[16];
    const int* aei       = (const int*)d_in[17];

    int E  = in_sizes[16];
    int Nn = in_sizes[0] / 64;
    const int* srcp = aei;
    const int* dstp = aei + E;

    float* wsf = (float*)d_ws;
    int*   wsi = (int*)d_ws;

    size_t o = IB;
    int* modep = wsi + o; o += 16;
    int* cnt   = wsi + o; o += Nn;
    o = (o + 63) & ~(size_t)63;
    int* pk    = wsi + o; o += (size_t)Nn * MAXD;
    float* Yp  = (float*)(wsi + o); o += (size_t)Nn * 64;
    float* XWp = (float*)(wsi + o); o += (size_t)Nn * 64;
    float* p2f = (float*)(wsi + o); o += (size_t)Nn * 64;
    // ws usage ~52 MB

    int NB = (Nn + 255) / 256;

    k_init<<<NB, 256, 0, stream>>>(bond_emb, edge_w, edge_b, pre_w1, pre_b1, pre_w2, pre_b2,
                                   post_w1, post_b1, post_w2, post_b2, lin_w, lin_b, ln_g, ln_b,
                                   atom_x, wsf, Yp, XWp, cnt, modep, Nn);
    k_scatter<<<(E + 255) / 256, 256, 0, stream>>>(dstp, srcp, bond_x, cnt, pk, wsf, E);
    dim3 gn((Nn + 3) / 4, 1, 1);
    k_node<<<gn, 256, 0, stream>>>(atom_x, Yp, XWp, pk, cnt, wsf, p2f, modep, Nn);
    k_final<<<(Nn + 15) / 16, 256, 0, stream>>>(atom_x, wsf, p2f, Yp, XWp, d_out, modep, Nn);
}

// Round 10
// 343.345 us; speedup vs baseline: 3.2090x; 1.0653x over previous
//
#include <hip/hip_runtime.h>
#include <cstdint>

typedef unsigned short u16;

#define AVG_LOG_F 1.4862356961977451f
#define MAXD 64

// ---- workspace float-unit offsets (weights region) ----
#define OFF_W1   0      // pre_w1  fp32 [4][48][16]
#define OFF_W2   3072   // pre_w2  fp32 [4][16][16]
#define OFF_PW1  4096   // post_w1 fp32 [4][256][16]
#define OFF_PW2  20480  // post_w2 fp32 [4][16][16]
#define OFF_LW   21504  // lin_w   fp32 [64][64]
#define OFF_PB1  25600
#define OFF_PB2  25664
#define OFF_QB1  25728
#define OFF_QB2  25792
#define OFF_LB   25856
#define OFF_LG   25920
#define OFF_LBN  25984
#define OFF_ET   26048  // e_table fp32 [5][16]
#define OFF_EWT  26128  // eWtab  fp32 [5][64]  (pb1 + ET.W1e, node-invariant)
#define IB       26448  // int region start (4B units)

__device__ __forceinline__ float bf2f(u16 u) {
    return __uint_as_float(((unsigned)u) << 16);
}
__device__ __forceinline__ u16 f2bf(float f) {
    unsigned u = __float_as_uint(f);
    u += 0x7fffu + ((u >> 16) & 1u);
    return (u16)(u >> 16);
}
__device__ __forceinline__ float rdin(const void* p, long j, int mode) {
    if (mode == 0) return bf2f(((const u16*)p)[j]);
    return ((const float*)p)[j];
}
template <int MODE>
__device__ __forceinline__ void load16c(const void* p, long base, float* o) {
    if (MODE == 0) {
        const u16* q = (const u16*)p + base;
        uint4 a = *(const uint4*)q;
        uint4 b = *(const uint4*)(q + 8);
        o[0]  = __uint_as_float(a.x << 16); o[1]  = __uint_as_float(a.x & 0xffff0000u);
        o[2]  = __uint_as_float(a.y << 16); o[3]  = __uint_as_float(a.y & 0xffff0000u);
        o[4]  = __uint_as_float(a.z << 16); o[5]  = __uint_as_float(a.z & 0xffff0000u);
        o[6]  = __uint_as_float(a.w << 16); o[7]  = __uint_as_float(a.w & 0xffff0000u);
        o[8]  = __uint_as_float(b.x << 16); o[9]  = __uint_as_float(b.x & 0xffff0000u);
        o[10] = __uint_as_float(b.y << 16); o[11] = __uint_as_float(b.y & 0xffff0000u);
        o[12] = __uint_as_float(b.z << 16); o[13] = __uint_as_float(b.z & 0xffff0000u);
        o[14] = __uint_as_float(b.w << 16); o[15] = __uint_as_float(b.w & 0xffff0000u);
    } else {
        const float* q = (const float*)p + base;
        float4 a = *(const float4*)q;
        float4 b = *(const float4*)(q + 4);
        float4 c = *(const float4*)(q + 8);
        float4 d = *(const float4*)(q + 12);
        o[0]=a.x; o[1]=a.y; o[2]=a.z; o[3]=a.w;
        o[4]=b.x; o[5]=b.y; o[6]=b.z; o[7]=b.w;
        o[8]=c.x; o[9]=c.y; o[10]=c.z; o[11]=c.w;
        o[12]=d.x; o[13]=d.y; o[14]=d.z; o[15]=d.w;
    }
}

// per-node precompute: Y[n][l] = x[n].W1_xj column,  XW[n][l] = x[n].W1_xi column
template <int MODE>
__device__ __forceinline__ void y_loop(const void* ax, const void* pre_w1, float* wsY, float* wsXW,
                                       int Nn, int wave, int nwaves, int l) {
    const int t = l >> 4, g = l & 15;
    float wxi[16], wxj[16];
#pragma unroll
    for (int f = 0; f < 16; f++) {
        wxi[f] = rdin(pre_w1, t * 768 + f * 16 + g, MODE);
        wxj[f] = rdin(pre_w1, t * 768 + (16 + f) * 16 + g, MODE);
    }
    for (int n = wave; n < Nn; n += nwaves) {
        float xj[16];
        load16c<MODE>(ax, (long)n * 64 + t * 16, xj);
        float accY = 0.f, accX = 0.f;
#pragma unroll
        for (int f = 0; f < 16; f++) {
            accY = fmaf(xj[f], wxj[f], accY);
            accX = fmaf(xj[f], wxi[f], accX);
        }
        wsY[(long)n * 64 + l]  = accY;
        wsXW[(long)n * 64 + l] = accX;
    }
}

// ---------------- 1: init: dtype, zero cnt, weights -> fp32, ET, Y, XW ----------------
__global__ __launch_bounds__(256) void k_init(
    const void* bond_emb, const void* edge_w, const void* edge_b,
    const void* pre_w1, const void* pre_b1, const void* pre_w2, const void* pre_b2,
    const void* post_w1, const void* post_b1, const void* post_w2, const void* post_b2,
    const void* lin_w, const void* lin_b, const void* ln_g, const void* ln_b,
    const void* ax, float* wsf, float* wsY, float* wsXW, int* cnt, int* modep, int Nn)
{
    __shared__ int csh;
    int tid = threadIdx.x;
    if (tid == 0) csh = 0;
    __syncthreads();
    {
        unsigned v = ((const unsigned*)ax)[tid];
        unsigned lo = v & 0xffffu;
        int e = (int)((lo >> 7) & 0xff);
        int isbf = (lo == 0u) || (e >= 110 && e <= 140);
        atomicAdd(&csh, isbf);
    }
    __syncthreads();
    int mode = (csh >= 192) ? 0 : 1;

    int gt = blockIdx.x * 256 + tid;
    int gs = gridDim.x * 256;
    if (gt < Nn) cnt[gt] = 0;
    if (blockIdx.x == 0 && tid == 0) modep[0] = mode;

    for (int j = gt; j < 3072; j += gs)  wsf[OFF_W1 + j]  = rdin(pre_w1, j, mode);
    for (int j = gt; j < 1024; j += gs)  wsf[OFF_W2 + j]  = rdin(pre_w2, j, mode);
    for (int j = gt; j < 16384; j += gs) wsf[OFF_PW1 + j] = rdin(post_w1, j, mode);
    for (int j = gt; j < 1024; j += gs)  wsf[OFF_PW2 + j] = rdin(post_w2, j, mode);
    for (int j = gt; j < 4096; j += gs)  wsf[OFF_LW + j]  = rdin(lin_w, j, mode);
    for (int j = gt; j < 64; j += gs) {
        wsf[OFF_PB1 + j] = rdin(pre_b1, j, mode);
        wsf[OFF_PB2 + j] = rdin(pre_b2, j, mode);
        wsf[OFF_QB1 + j] = rdin(post_b1, j, mode);
        wsf[OFF_QB2 + j] = rdin(post_b2, j, mode);
        wsf[OFF_LB + j]  = rdin(lin_b, j, mode);
        wsf[OFF_LG + j]  = rdin(ln_g, j, mode);
        wsf[OFF_LBN + j] = rdin(ln_b, j, mode);
    }
    if (gt < 80) {
        int b = gt >> 4, f = gt & 15;
        float acc = rdin(edge_b, f, mode);
        for (int k = 0; k < 64; k++)
            acc = fmaf(rdin(bond_emb, b * 64 + k, mode), rdin(edge_w, k * 16 + f, mode), acc);
        wsf[OFF_ET + gt] = acc;
    }
    int wave = gt >> 6;
    int nwaves = gs >> 6;
    int l = tid & 63;
    if (mode == 0) y_loop<0>(ax, pre_w1, wsY, wsXW, Nn, wave, nwaves, l);
    else           y_loop<1>(ax, pre_w1, wsY, wsXW, Nn, wave, nwaves, l);
}

// ---------------- 2: count+scatter into fixed-stride buckets; block 0 also builds eWtab ----
__global__ __launch_bounds__(256) void k_scatter(
    const int* __restrict__ dstp, const int* __restrict__ srcp, const int* __restrict__ bondp,
    int* __restrict__ cnt, int* __restrict__ pk, float* __restrict__ wsf, int E)
{
    if (blockIdx.x == 0) {
        for (int j = threadIdx.x; j < 320; j += 256) {
            int b = j >> 6, ll = j & 63, tt = ll >> 4, gg = ll & 15;
            float acc = wsf[OFF_PB1 + tt * 16 + gg];
#pragma unroll
            for (int f = 0; f < 16; f++)
                acc = fmaf(wsf[OFF_ET + b * 16 + f], wsf[OFF_W1 + tt * 768 + (32 + f) * 16 + gg], acc);
            wsf[OFF_EWT + j] = acc;
        }
    }
    int e = blockIdx.x * 256 + threadIdx.x;
    if (e < E) {
        int d = dstp[e];
        int pos = atomicAdd(&cnt[d], 1);
        if (pos < MAXD) pk[d * MAXD + pos] = (srcp[e] << 3) | (bondp[e] & 7);
    }
}

// ---------------- 3: wave-per-node fully-fused kernel (messages..LayerNorm..residual) ------
__global__ __launch_bounds__(256, 4) void k_node(
    const void* __restrict__ ax, const float* __restrict__ Yp, const float* __restrict__ XWp,
    const int* __restrict__ pk, const int* __restrict__ cnt,
    const float* __restrict__ wsf, void* __restrict__ outp,
    const int* __restrict__ modep, int Nn)
{
    __shared__ float hb[4][16][64];
    __shared__ float zws[4][5][64];
    const int w = threadIdx.x >> 6;
    const int l = threadIdx.x & 63;
    const int t = l >> 4;
    const int g = l & 15;
    const int n = blockIdx.x * 4 + w;
    const int mode = modep[0];
    const bool active = (n < Nn);
    const int nn = active ? n : 0;

    const float* W2  = wsf + OFF_W2  + t * 256;
    const float* PW1 = wsf + OFF_PW1 + t * 4096;
    const float* PW2 = wsf + OFF_PW2 + t * 256;

    float w2c[16], pw2c[16];
#pragma unroll
    for (int f = 0; f < 16; f++) {
        w2c[f]  = W2[f * 16 + g];
        pw2c[f] = PW2[f * 16 + g];
    }
    float pb2g = wsf[OFF_PB2 + t * 16 + g];
    float qb1g = wsf[OFF_QB1 + t * 16 + g];
    float qb2g = wsf[OFF_QB2 + t * 16 + g];

    int deg = active ? cnt[nn] : 0;
    if (deg > MAXD) deg = MAXD;

    int   pkvAll = pk[nn * MAXD + l];
    float XWv    = XWp[(long)nn * 64 + l];
    zws[w][0][l] = XWv + wsf[OFF_EWT + 0 * 64 + l];
    zws[w][1][l] = XWv + wsf[OFF_EWT + 1 * 64 + l];
    zws[w][2][l] = XWv + wsf[OFF_EWT + 2 * 64 + l];
    zws[w][3][l] = XWv + wsf[OFF_EWT + 3 * 64 + l];
    zws[w][4][l] = XWv + wsf[OFF_EWT + 4 * 64 + l];

    float xi[16];
    if (mode == 0) load16c<0>(ax, (long)nn * 64 + t * 16, xi);
    else           load16c<1>(ax, (long)nn * 64 + t * 16, xi);

    float s = 0.f, s2 = 0.f, mn = 3.0e38f, mx = -3.0e38f;

    auto phaseA = [&](int srclane, int k) {
        int v = __builtin_amdgcn_readlane(pkvAll, srclane);
        float yv = Yp[((long)(v >> 3) << 6) + l];
        float zt = zws[w][v & 7][l];
        hb[w][k][l] = fmaxf(yv + zt, 0.f);
    };
    auto phaseB = [&](int k) {
        const float4* hp = (const float4*)&hb[w][k][t * 16];
        float4 h0 = hp[0], h1 = hp[1], h2 = hp[2], h3 = hp[3];
        float m = pb2g;
        m = fmaf(h0.x, w2c[0],  m); m = fmaf(h0.y, w2c[1],  m);
        m = fmaf(h0.z, w2c[2],  m); m = fmaf(h0.w, w2c[3],  m);
        m = fmaf(h1.x, w2c[4],  m); m = fmaf(h1.y, w2c[5],  m);
        m = fmaf(h1.z, w2c[6],  m); m = fmaf(h1.w, w2c[7],  m);
        m = fmaf(h2.x, w2c[8],  m); m = fmaf(h2.y, w2c[9],  m);
        m = fmaf(h2.z, w2c[10], m); m = fmaf(h2.w, w2c[11], m);
        m = fmaf(h3.x, w2c[12], m); m = fmaf(h3.y, w2c[13], m);
        m = fmaf(h3.z, w2c[14], m); m = fmaf(h3.w, w2c[15], m);
        s += m;
        s2 = fmaf(m, m, s2);
        mn = fminf(mn, m);
        mx = fmaxf(mx, m);
    };

#pragma unroll
    for (int kb = 0; kb < MAXD; kb += 16) {
        if (kb >= deg) break;
        int B = deg - kb; if (B > 16) B = 16;
        if (B == 16) {
#pragma unroll
            for (int k = 0; k < 16; k++) phaseA(kb + k, k);   // literal lanes -> v_readlane
#pragma unroll 4
            for (int k = 0; k < 16; k++) phaseB(k);
        } else {
            for (int k = 0; k < B; k++) phaseA(kb + k, k);
            for (int k = 0; k < B; k++) phaseB(k);
        }
    }

    if (deg == 0) { mn = 0.f; mx = 0.f; }
    float cf = (float)(deg > 0 ? deg : 1);
    float inv = 1.0f / cf;
    float mean = s * inv;
    float var = s2 * inv - mean * mean;
    float sd = sqrtf(fmaxf(var, 0.f) + 1e-5f);
    float ldv = logf(cf + 1.0f);
    float sc1 = ldv * (1.0f / AVG_LOG_F);
    float sc2 = AVG_LOG_F / ldv;

    hb[w][0][l] = s;
    hb[w][1][l] = mean;
    hb[w][2][l] = mn;
    hb[w][3][l] = mx;
    hb[w][4][l] = sd;

    float p1 = qb1g;
#pragma unroll
    for (int f = 0; f < 16; f++) p1 = fmaf(xi[f], PW1[f * 16 + g], p1);
#pragma unroll
    for (int a = 0; a < 5; a++) {
        const float4* ap = (const float4*)&hb[w][a][t * 16];
        float4 a0 = ap[0], a1 = ap[1], a2 = ap[2], a3 = ap[3];
        float av[16] = {a0.x,a0.y,a0.z,a0.w, a1.x,a1.y,a1.z,a1.w,
                        a2.x,a2.y,a2.z,a2.w, a3.x,a3.y,a3.z,a3.w};
        int rb = 16 + a * 16;
#pragma unroll
        for (int f = 0; f < 16; f++) {
            float wv = fmaf(sc2, PW1[(rb + 160 + f) * 16 + g],
                       fmaf(sc1, PW1[(rb + 80 + f) * 16 + g],
                                 PW1[(rb + f) * 16 + g]));
            p1 = fmaf(av[f], wv, p1);
        }
    }
    p1 = fmaxf(p1, 0.f);

    hb[w][5][l] = p1;
    float m2 = qb2g;
    {
        const float4* pp = (const float4*)&hb[w][5][t * 16];
        float4 p0 = pp[0], q1 = pp[1], q2 = pp[2], q3 = pp[3];
        m2 = fmaf(p0.x, pw2c[0],  m2); m2 = fmaf(p0.y, pw2c[1],  m2);
        m2 = fmaf(p0.z, pw2c[2],  m2); m2 = fmaf(p0.w, pw2c[3],  m2);
        m2 = fmaf(q1.x, pw2c[4],  m2); m2 = fmaf(q1.y, pw2c[5],  m2);
        m2 = fmaf(q1.z, pw2c[6],  m2); m2 = fmaf(q1.w, pw2c[7],  m2);
        m2 = fmaf(q2.x, pw2c[8],  m2); m2 = fmaf(q2.y, pw2c[9],  m2);
        m2 = fmaf(q2.z, pw2c[10], m2); m2 = fmaf(q2.w, pw2c[11], m2);
        m2 = fmaf(q3.x, pw2c[12], m2); m2 = fmaf(q3.y, pw2c[13], m2);
        m2 = fmaf(q3.z, pw2c[14], m2); m2 = fmaf(q3.w, pw2c[15], m2);
    }

    // ---- fused final: 64x64 linear + LayerNorm + ReLU + residual (was k_final) ----
    hb[w][5][l] = m2;                       // p2 row of this node, one float per lane
    const float* LW = wsf + OFF_LW;
    float a = wsf[OFF_LB + l];
#pragma unroll
    for (int f = 0; f < 64; f++)
        a = fmaf(hb[w][5][f], LW[f * 64 + l], a);   // broadcast LDS read + L1-hot LW row

    float s1 = a, sq = a * a;
#pragma unroll
    for (int o = 1; o < 64; o <<= 1) { s1 += __shfl_xor(s1, o); sq += __shfl_xor(sq, o); }
    float mu = s1 * (1.0f / 64.0f);
    float varl = sq * (1.0f / 64.0f) - mu * mu;
    float ln = (a - mu) * rsqrtf(varl + 1e-5f) * wsf[OFF_LG + l] + wsf[OFF_LBN + l];
    if (active) {
        long idx = (long)n * 64 + l;
        float res = rdin(ax, idx, mode) + fmaxf(ln, 0.f);
        if (mode == 0) ((u16*)outp)[idx] = f2bf(res);
        else           ((float*)outp)[idx] = res;
    }
}

extern "C" void kernel_launch(void* const* d_in, const int* in_sizes, int n_in,
                              void* d_out, int out_size, void* d_ws, size_t ws_size,
                              hipStream_t stream) {
    const void* atom_x   = d_in[0];
    const void* bond_emb = d_in[1];
    const void* edge_w   = d_in[2];
    const void* edge_b   = d_in[3];
    const void* pre_w1   = d_in[4];
    const void* pre_b1   = d_in[5];
    const void* pre_w2   = d_in[6];
    const void* pre_b2   = d_in[7];
    const void* post_w1  = d_in[8];
    const void* post_b1  = d_in[9];
    const void* post_w2  = d_in[10];
    const void* post_b2  = d_in[11];
    const void* lin_w    = d_in[12];
    const void* lin_b    = d_in[13];
    const void* ln_g     = d_in[14];
    const void* ln_b     = d_in[15];
    const int* bond_x    = (const int*)d_in[16];
    const int* aei       = (const int*)d_in[17];

    int E  = in_sizes[16];
    int Nn = in_sizes[0] / 64;
    const int* srcp = aei;
    const int* dstp = aei + E;

    float* wsf = (float*)d_ws;
    int*   wsi = (int*)d_ws;

    size_t o = IB;
    int* modep = wsi + o; o += 16;
    int* cnt   = wsi + o; o += Nn;
    o = (o + 63) & ~(size_t)63;
    int* pk    = wsi + o; o += (size_t)Nn * MAXD;
    float* Yp  = (float*)(wsi + o); o += (size_t)Nn * 64;
    float* XWp = (float*)(wsi + o); o += (size_t)Nn * 64;
    // ws usage ~39 MB

    k_init<<<1600, 256, 0, stream>>>(bond_emb, edge_w, edge_b, pre_w1, pre_b1, pre_w2, pre_b2,
                                     post_w1, post_b1, post_w2, post_b2, lin_w, lin_b, ln_g, ln_b,
                                     atom_x, wsf, Yp, XWp, cnt, modep, Nn);
    k_scatter<<<(E + 255) / 256, 256, 0, stream>>>(dstp, srcp, bond_x, cnt, pk, wsf, E);
    dim3 gn((Nn + 3) / 4, 1, 1);
    k_node<<<gn, 256, 0, stream>>>(atom_x, Yp, XWp, pk, cnt, wsf, d_out, modep, Nn);
}